// Round 6
// baseline (645.779 us; speedup 1.0000x reference)
//
#include <hip/hip_runtime.h>
#include <hip/hip_bf16.h>
#include <math.h>

#define BB    512
#define NPG   34
#define NT    17408
#define FEAT  1152
#define GPD   2048
#define HID   1024
#define NH    8
#define AD    64
#define HA    512
#define LLM   4096
#define EPG   272
#define NE    139264
#define C32   24576
#define CC    768

#define AS3 __attribute__((address_space(3)))
#define AS1 __attribute__((address_space(1)))

typedef __attribute__((ext_vector_type(8))) short short8v;
typedef __attribute__((ext_vector_type(4))) float f32x4;

__device__ __forceinline__ ushort f2bf(float f) {
    __hip_bfloat16 h = __float2bfloat16(f);
    return __builtin_bit_cast(ushort, h);
}

// ---------------- transpose body: W[R][Cn] -> bf16 WT[Cn][R] ----------------
__device__ __forceinline__ void d_transpose(const float* __restrict__ W, ushort* __restrict__ WT,
                                            int R, int Cn, int bx, int by,
                                            float (*tile)[33], int tid) {
    int c0 = bx * 32, r0 = by * 32;
    int tc = tid & 31, tr = tid >> 5;
#pragma unroll
    for (int i = 0; i < 4; i++)
        tile[tr + i * 8][tc] = W[(size_t)(r0 + tr + i * 8) * Cn + c0 + tc];
    __syncthreads();
#pragma unroll
    for (int it = 0; it < 2; it++) {
        int p = tid + it * 256;
        int c = p >> 4, pr = (p & 15) << 1;
        ushort2 v;
        v.x = f2bf(tile[pr][c]);
        v.y = f2bf(tile[pr + 1][c]);
        *(ushort2*)&WT[(size_t)(c0 + c) * R + r0 + pr] = v;
    }
}

// ---------------- pool body: [B,768,8,8,4] -> bf16 [B,24576] (2x2x2 mean) ----------------
__device__ __forceinline__ void d_pool(const float* __restrict__ gf, ushort* __restrict__ outB,
                                       int blk, int tid) {
    int t = blk * 256 + tid;
    int q = t & 15; int bc = t >> 4;
    int dO = q >> 2, hO = q & 3;
    const float* p = gf + (size_t)bc * 256 + dO * 64 + hO * 8;
    float4 r00 = *(const float4*)(p);
    float4 r01 = *(const float4*)(p + 4);
    float4 r10 = *(const float4*)(p + 32);
    float4 r11 = *(const float4*)(p + 36);
    float o0 = (r00.x + r00.y + r01.x + r01.y + r10.x + r10.y + r11.x + r11.y) * 0.125f;
    float o1 = (r00.z + r00.w + r01.z + r01.w + r10.z + r10.w + r11.z + r11.w) * 0.125f;
    int b = bc / CC, c = bc % CC;
    ushort2 v; v.x = f2bf(o0); v.y = f2bf(o1);
    *(ushort2*)(outB + (size_t)b * C32 + c * 32 + dO * 8 + hO * 2) = v;
}

// ---------------- fused prep: 5 weight transposes + pool, one launch ----------------
__global__ __launch_bounds__(256) void k_prep(
    const float* __restrict__ W1g, ushort* __restrict__ W1gT,
    const float* __restrict__ W2g, ushort* __restrict__ W2gT,
    const float* __restrict__ Wp,  ushort* __restrict__ WpT,
    const float* __restrict__ Wg,  ushort* __restrict__ WgT,
    const float* __restrict__ Wllm, ushort* __restrict__ WllmT,
    const float* __restrict__ gf,  ushort* __restrict__ poolB) {
    __shared__ float tile[32][33];
    int blk = blockIdx.x, tid = threadIdx.x;
    if (blk < 49152) {
        d_transpose(W1g, W1gT, C32, GPD, blk & 63, blk >> 6, tile, tid);
    } else if (blk < 51456) {
        int l = blk - 49152; d_transpose(W2g, W2gT, GPD, FEAT, l % 36, l / 36, tile, tid);
    } else if (blk < 52608) {
        int l = blk - 51456; d_transpose(Wp, WpT, FEAT, HID, l & 31, l >> 5, tile, tid);
    } else if (blk < 53120) {
        int l = blk - 52608; d_transpose(Wg, WgT, HID, HA, l & 15, l >> 4, tile, tid);
    } else if (blk < 55168) {
        int l = blk - 53120; d_transpose(Wllm, WllmT, HA, LLM, l & 127, l >> 7, tile, tid);
    } else {
        d_pool(gf, poolB, blk - 55168, tid);
    }
}

// ================= 256x256 8-phase bf16 MFMA GEMM (T2+T3+T4+T5) =================
// K-loop schedule identical to the round-4 verified template. ZMAJ: z-major
// bijective XCD ordering so split-K blocks sharing a B-panel are XCD-contiguous.
#define GLDS(gp, lp) __builtin_amdgcn_global_load_lds((const AS1 void*)(gp), (AS3 void*)(lp), 16, 0, 0)
#define STAGE_A(buf, h, tt) { \
    const ushort* s_ = gAs + (size_t)(tt) * 64 + (size_t)(2 * (h)) * rK; \
    ushort* d_ = lds + (buf) * 32768 + (2 * (h)) * 4096 + (w << 9); \
    GLDS(s_, d_); GLDS(s_ + rK, d_ + 4096); }
#define STAGE_B(buf, h, tt) { \
    const ushort* s_ = gBs + (size_t)(tt) * 64 + (size_t)(2 * (h)) * rK; \
    ushort* d_ = lds + (buf) * 32768 + 16384 + (2 * (h)) * 4096 + (w << 9); \
    GLDS(s_, d_); GLDS(s_ + rK, d_ + 4096); }
#define DSRA(BO, mh) { _Pragma("unroll") for (int mf = 0; mf < 4; mf++) { \
    const ushort* p_ = lds + (BO) + aBase + ((mh) * 64 + mf * 16) * 64; \
    aF[mf][0] = *(const short8v*)(p_ + k0s); \
    aF[mf][1] = *(const short8v*)(p_ + k1s); } }
#define DSRB(BO, nh, BF) { _Pragma("unroll") for (int nf = 0; nf < 2; nf++) { \
    const ushort* p_ = lds + (BO) + bBase + ((nh) * 32 + nf * 16) * 64; \
    BF[nf][0] = *(const short8v*)(p_ + k0s); \
    BF[nf][1] = *(const short8v*)(p_ + k1s); } }
#define MM(mh, nh, BF) { \
    asm volatile("s_waitcnt lgkmcnt(0)" ::: "memory"); \
    __builtin_amdgcn_sched_barrier(0); \
    __builtin_amdgcn_s_setprio(1); \
    _Pragma("unroll") for (int mf = 0; mf < 4; mf++) \
    _Pragma("unroll") for (int nf = 0; nf < 2; nf++) { \
        acc[(mh)*4+mf][(nh)*2+nf] = __builtin_amdgcn_mfma_f32_16x16x32_bf16(aF[mf][0], BF[nf][0], acc[(mh)*4+mf][(nh)*2+nf], 0, 0, 0); \
        acc[(mh)*4+mf][(nh)*2+nf] = __builtin_amdgcn_mfma_f32_16x16x32_bf16(aF[mf][1], BF[nf][1], acc[(mh)*4+mf][(nh)*2+nf], 0, 0, 0); } \
    __builtin_amdgcn_s_setprio(0); }
#define BAR __builtin_amdgcn_s_barrier()
#define VMW4 { asm volatile("s_waitcnt vmcnt(4)" ::: "memory"); __builtin_amdgcn_sched_barrier(0); }

template<bool SPLITK, bool ZMAJ, bool BIAS, bool RELU, bool OUTBF>
__global__ __launch_bounds__(512, 2) void k_gemm256(
    const ushort* __restrict__ A, const ushort* __restrict__ BT,
    const float* __restrict__ bias, void* __restrict__ Cout,
    int M, int N, int K, int kChunk) {
    __shared__ ushort lds[65536];            // 128 KiB: [buf][A 32KB | B 32KB]
    const int t = threadIdx.x;
    const int w = t >> 6, l = t & 63;
    const int wm = w >> 2, wn = w & 3;
    int m0, n0, kz = 0;
    {
        const int gx = gridDim.x, gy = gridDim.y;
        if (ZMAJ) {
            const int nwg = gx * gy * gridDim.z;
            const int id = (blockIdx.z * gx + blockIdx.x) * gy + blockIdx.y;
            const int qc = nwg >> 3, rc = nwg & 7;
            const int xcd = id & 7, pos = id >> 3;
            const int nid = (xcd < rc ? xcd * (qc + 1) : rc * (qc + 1) + (xcd - rc) * qc) + pos;
            const int y = nid % gy; const int r2 = nid / gy;
            const int x = r2 % gx; kz = r2 / gx;
            m0 = y * 256; n0 = x * 256;
        } else {
            const int nwg = gx * gy;
            const int id = blockIdx.y * gx + blockIdx.x;
            const int qc = nwg >> 3, rc = nwg & 7;
            const int xcd = id & 7, pos = id >> 3;
            const int nid = (xcd < rc ? xcd * (qc + 1) : rc * (qc + 1) + (xcd - rc) * qc) + pos;
            m0 = (nid / gx) * 256; n0 = (nid % gx) * 256;
            kz = blockIdx.z;
        }
    }
    const int kBase = SPLITK ? kz * kChunk : 0;
    const int NTt = (SPLITK ? kChunk : K) / 64;

    // staging source: linear LDS dest; inverse swizzle folded into global k-offset
    const int rowLo = t >> 3;
    const int keSrc = ((t & 7) << 3) ^ (((rowLo >> 2) & 1) << 5) ^ (((rowLo >> 3) & 1) << 4);
    const ushort* gAs = A + (size_t)(m0 + rowLo) * K + kBase + keSrc;
    const ushort* gBs = BT + (size_t)(n0 + rowLo) * K + kBase + keSrc;
    const size_t rK = (size_t)64 * K;

    // fragment read geometry (swizzled ds_read addresses)
    const int fcol = l & 15, fk = (l >> 4) << 3;
    const int flipR = (((l >> 2) & 1) << 5) | (((l >> 3) & 1) << 4);
    const int k0s = fk ^ flipR;
    const int k1s = fk ^ 32 ^ flipR;
    const int aBase = (wm * 128 + fcol) * 64;
    const int bBase = 16384 + (wn * 64 + fcol) * 64;

    short8v aF[4][2], bF0[2][2], bF1[2][2];
    f32x4 acc[8][4] = {};

    // prologue: tile0 {B0,B1,A0,A1} + tile1 {B0,B1}; confirm tile0
    STAGE_B(0, 0, 0); STAGE_B(0, 1, 0); STAGE_A(0, 0, 0); STAGE_A(0, 1, 0);
    STAGE_B(1, 0, 1); STAGE_B(1, 1, 1);
    VMW4;
    BAR;

    const int NITER = NTt >> 1;
    for (int it = 0; it < NITER; ++it) {
        const int t1 = 2 * it + 1;
        const int t2r = 2 * it + 2, t3r = 2 * it + 3;
        const int t2 = t2r < NTt ? t2r : 0;   // clamped dummies keep vmcnt uniform
        const int t3 = t3r < NTt ? t3r : 0;
        DSRA(0, 0); DSRB(0, 0, bF0); STAGE_A(1, 0, t1);
        BAR; MM(0, 0, bF0); BAR;
        DSRB(0, 1, bF1); STAGE_A(1, 1, t1);
        BAR; MM(0, 1, bF1); BAR;
        DSRA(0, 1); STAGE_B(0, 0, t2);
        BAR; MM(1, 1, bF1); BAR;
        STAGE_B(0, 1, t2); VMW4;
        BAR; MM(1, 0, bF0); BAR;
        DSRA(32768, 0); DSRB(32768, 0, bF0); STAGE_A(0, 0, t2);
        BAR; MM(0, 0, bF0); BAR;
        DSRB(32768, 1, bF1); STAGE_A(0, 1, t2);
        BAR; MM(0, 1, bF1); BAR;
        DSRA(32768, 1); STAGE_B(1, 0, t3);
        BAR; MM(1, 1, bF1); BAR;
        STAGE_B(1, 1, t3); VMW4;
        BAR; MM(1, 0, bF0); BAR;
    }
    asm volatile("s_waitcnt vmcnt(0)" ::: "memory");
    BAR;   // all waves drained their in-flight LDS writes before LDS reuse

    // ---- LDS-staged vectorized epilogue: 4 passes of 32 rows x 64 cols f32 ----
    const int orow = (l >> 4) << 2;
    float* eph = ((float*)lds) + w * 2176;   // wave-private 32x68 f32 (8.5 KB)
    const int ecol = (l & 15) << 2;
    const int erow4 = l >> 4;
#pragma unroll
    for (int pass = 0; pass < 4; pass++) {
#pragma unroll
        for (int mi = 0; mi < 2; mi++) {
            int mf = pass * 2 + mi;
#pragma unroll
            for (int nf = 0; nf < 4; nf++)
#pragma unroll
                for (int r = 0; r < 4; r++)
                    eph[(mi * 16 + orow + r) * 68 + nf * 16 + fcol] = acc[mf][nf][r];
        }
#pragma unroll
        for (int g = 0; g < 8; g++) {
            int lrow = g * 4 + erow4;
            f32x4 v = *(f32x4*)&eph[lrow * 68 + ecol];
            int row = m0 + wm * 128 + pass * 32 + lrow;
            int col = n0 + wn * 64 + ecol;
            if (BIAS) {
                float4 bb = *(const float4*)(bias + col);
                v[0] += bb.x; v[1] += bb.y; v[2] += bb.z; v[3] += bb.w;
            }
            if (RELU) {
#pragma unroll
                for (int q = 0; q < 4; q++) v[q] = v[q] > 0.f ? v[q] : 0.f;
            }
            if (OUTBF) {
                ushort4 u;
                u.x = f2bf(v[0]); u.y = f2bf(v[1]); u.z = f2bf(v[2]); u.w = f2bf(v[3]);
                *(ushort4*)&((ushort*)Cout)[(size_t)row * N + col] = u;
            } else {
                size_t off = (size_t)row * N + col;
                if (SPLITK) off += (size_t)kz * (size_t)M * N;
                float4 fv = {v[0], v[1], v[2], v[3]};
                *(float4*)&((float*)Cout)[off] = fv;
            }
        }
    }
}

// ---------------- 128x128 m97-style bf16 GEMM (kept for GEMM2, N=1152) ----------------
template<bool SPLITK, bool BIAS, bool RELU, bool OUTBF>
__global__ __launch_bounds__(256) void k_gemm_bf(
    const ushort* __restrict__ A, const ushort* __restrict__ BT,
    const float* __restrict__ bias, void* __restrict__ Cout,
    int M, int N, int K, int kChunk) {
    __shared__ ushort lA[128 * 32];
    __shared__ ushort lB[128 * 32];
    const int t = threadIdx.x;
    const int w = t >> 6, l = t & 63;
    const int m0 = blockIdx.y * 128, n0 = blockIdx.x * 128;
    const int kLen = SPLITK ? kChunk : K;
    const int k0 = SPLITK ? blockIdx.z * kChunk : 0;
    const int srow = w * 16 + (l >> 2);
    const int skq = (l & 3) << 3;
    const ushort* gA = A + (size_t)(m0 + srow) * K + k0 + skq;
    const ushort* gB = BT + (size_t)(n0 + srow) * K + k0 + skq;
    ushort* lA0 = lA + w * 512;
    ushort* lB0 = lB + w * 512;
    const size_t str64 = (size_t)64 * K;
    const int wr = (w >> 1) << 6, wc = (w & 1) << 6;
    const int fcol = l & 15, fk = (l >> 4) << 3;

    f32x4 acc[4][4] = {};
    for (int kk = 0; kk < kLen; kk += 32) {
        __syncthreads();
        GLDS(gA + kk,         lA0);
        GLDS(gA + kk + str64, lA0 + 2048);
        GLDS(gB + kk,         lB0);
        GLDS(gB + kk + str64, lB0 + 2048);
        __syncthreads();
        short8v a[4], b[4];
#pragma unroll
        for (int f = 0; f < 4; f++) {
            a[f] = *(const short8v*)(lA + (wr + f * 16 + fcol) * 32 + fk);
            b[f] = *(const short8v*)(lB + (wc + f * 16 + fcol) * 32 + fk);
        }
#pragma unroll
        for (int i = 0; i < 4; i++)
#pragma unroll
            for (int j = 0; j < 4; j++)
                acc[i][j] = __builtin_amdgcn_mfma_f32_16x16x32_bf16(a[i], b[j], acc[i][j], 0, 0, 0);
    }
    const int orow = (l >> 4) << 2;
#pragma unroll
    for (int i = 0; i < 4; i++) {
#pragma unroll
        for (int j = 0; j < 4; j++) {
            int col = n0 + wc + j * 16 + fcol;
            float bv = BIAS ? bias[col] : 0.f;
#pragma unroll
            for (int r = 0; r < 4; r++) {
                int row = m0 + wr + i * 16 + orow + r;
                float v = acc[i][j][r] + bv;
                if (RELU) v = v > 0.f ? v : 0.f;
                if (OUTBF) {
                    ((ushort*)Cout)[(size_t)row * N + col] = f2bf(v);
                } else {
                    size_t off = (size_t)row * N + col;
                    if (SPLITK) off += (size_t)blockIdx.z * (size_t)M * N;
                    ((float*)Cout)[off] = v;
                }
            }
        }
    }
}

// ---------------- reduce split-K partials + bias (+relu) -> bf16 ----------------
template<int NP, bool RELU>
__global__ __launch_bounds__(256) void k_red(const float* __restrict__ part,
                                             const float* __restrict__ bias,
                                             ushort* __restrict__ outB,
                                             int N, int stride) {
    int i = blockIdx.x * 256 + threadIdx.x;
    float s = bias[i % N];
#pragma unroll
    for (int q = 0; q < NP; q++) s += part[i + (size_t)q * stride];
    if (RELU) s = s > 0.f ? s : 0.f;
    outB[i] = f2bf(s);
}

// ---------------- build bf16 node matrix [NT][FEAT] ----------------
__global__ __launch_bounds__(256) void k_nodes(const ushort* __restrict__ outgB,
                                               const float* __restrict__ locf,
                                               ushort* __restrict__ nodesB) {
    int idx = blockIdx.x * 256 + threadIdx.x;   // over NT*144 = 2,506,752 16B-chunks
    int node = idx / 144, cc = idx - node * 144;
    int b = node / NPG, j = node - b * NPG;
    int c = cc * 8;
    ushort* dst = nodesB + (size_t)node * FEAT + c;
    if (j == 0) {
        *(uint4*)dst = *(const uint4*)(outgB + (size_t)b * FEAT + c);
    } else {
        const float* s = locf + ((size_t)b * 33 + (j - 1)) * FEAT + c;
        float4 v0 = *(const float4*)s, v1 = *(const float4*)(s + 4);
        ushort u[8] = {f2bf(v0.x), f2bf(v0.y), f2bf(v0.z), f2bf(v0.w),
                       f2bf(v1.x), f2bf(v1.y), f2bf(v1.z), f2bf(v1.w)};
        *(uint4*)dst = *(uint4*)u;
    }
}

// ---------------- fused z-GEMM + GAT: one block per graph ----------------
// phase 1: z[34][512] = h[b*34..][1024] x Wg (reg-resident MFMA, bitwise-identical
// accumulation order to the former GEMM4); phase 2: scores/softmax/agg on LDS z.
__global__ __launch_bounds__(512) void k_zgat(const int* __restrict__ es, const int* __restrict__ ed,
                                              const ushort* __restrict__ hB,
                                              const ushort* __restrict__ WgT,
                                              const float* __restrict__ a_src,
                                              const float* __restrict__ a_dst,
                                              ushort* __restrict__ gnnB) {
    __shared__ float zt[NPG][521];
    __shared__ float sps[NPG][NH], spd[NPG][NH], smx[NPG][NH], sden[NPG][NH];
    __shared__ float esc[EPG][NH];
    __shared__ int srcl[EPG], dll[EPG], order[EPG], cnt[NPG], bstart[NPG + 1];
    const int b = blockIdx.x, t = threadIdx.x;
    const int w = t >> 6, l = t & 63;
    const int lm = l & 15, lh = l >> 4;

    // ---- phase 1: z = h x Wg ----
    f32x4 acc[3][4] = {};
    const ushort* hrow[3];
    bool hval[3];
#pragma unroll
    for (int mi = 0; mi < 3; mi++) {
        int row = mi * 16 + lm;
        hval[mi] = row < NPG;
        hrow[mi] = hB + ((size_t)b * NPG + (hval[mi] ? row : 0)) * HID + lh * 8;
    }
    const ushort* brow[4];
#pragma unroll
    for (int q = 0; q < 4; q++)
        brow[q] = WgT + (size_t)((w * 4 + q) * 16 + lm) * HID + lh * 8;
    const short8v zerov = {};
#pragma unroll 2
    for (int ks = 0; ks < 32; ks++) {
        const int kb = ks * 32;
        short8v af[3], bf[4];
#pragma unroll
        for (int mi = 0; mi < 3; mi++) {
            short8v v = *(const short8v*)(hrow[mi] + kb);
            af[mi] = hval[mi] ? v : zerov;
        }
#pragma unroll
        for (int q = 0; q < 4; q++) bf[q] = *(const short8v*)(brow[q] + kb);
#pragma unroll
        for (int mi = 0; mi < 3; mi++)
#pragma unroll
            for (int q = 0; q < 4; q++)
                acc[mi][q] = __builtin_amdgcn_mfma_f32_16x16x32_bf16(af[mi], bf[q], acc[mi][q], 0, 0, 0);
    }
#pragma unroll
    for (int mi = 0; mi < 3; mi++)
#pragma unroll
        for (int q = 0; q < 4; q++)
#pragma unroll
            for (int r = 0; r < 4; r++) {
                int m = mi * 16 + lh * 4 + r;
                if (m < NPG) zt[m][(w * 4 + q) * 16 + lm] = acc[mi][q][r];
            }
    // edges + histogram init
    for (int e = t; e < EPG; e += 512) {
        srcl[e] = es[b * EPG + e] - b * NPG;
        dll[e]  = ed[b * EPG + e] - b * NPG;
    }
    if (t < NPG) cnt[t] = 0;
    __syncthreads();

    // ---- phase 2: GAT (identical math/order to verified k_gat) ----
    for (int n = w; n < NPG; n += 8) {
        float s[NH], d[NH];
#pragma unroll
        for (int i = 0; i < NH; i++) {
            float zv = zt[n][i * 64 + l];
            s[i] = zv * a_src[i * 64 + l];
            d[i] = zv * a_dst[i * 64 + l];
        }
#pragma unroll
        for (int i = 0; i < NH; i++) {
#pragma unroll
            for (int off = 32; off > 0; off >>= 1) {
                s[i] += __shfl_xor(s[i], off);
                d[i] += __shfl_xor(d[i], off);
            }
        }
        if (l == 0) {
#pragma unroll
            for (int i = 0; i < NH; i++) { sps[n][i] = s[i]; spd[n][i] = d[i]; }
        }
    }
    for (int e = t; e < EPG; e += 512) atomicAdd(&cnt[dll[e]], 1);
    __syncthreads();
    if (t == 0) {   // deterministic serial prefix + scatter (ascending edge order)
        int s = 0;
        for (int n = 0; n < NPG; n++) { bstart[n] = s; s += cnt[n]; cnt[n] = bstart[n]; }
        bstart[NPG] = s;
        for (int e = 0; e < EPG; e++) order[cnt[dll[e]]++] = e;
    }
    __syncthreads();
    for (int i = t; i < EPG * NH; i += 512) {
        int e = i >> 3, h = i & 7;
        float sc = sps[srcl[e]][h] + spd[dll[e]][h];
        esc[e][h] = sc > 0.f ? sc : 0.2f * sc;
    }
    __syncthreads();
    for (int i = t; i < NPG * NH; i += 512) {
        int n = i >> 3, h = i & 7;
        float m = -INFINITY;
        for (int j = bstart[n]; j < bstart[n + 1]; j++) m = fmaxf(m, esc[order[j]][h]);
        if (m == -INFINITY) m = 0.f;
        float den = 0.f;
        for (int j = bstart[n]; j < bstart[n + 1]; j++) den += expf(esc[order[j]][h] - m);
        smx[n][h] = m; sden[n][h] = den;
    }
    __syncthreads();
    for (int i = t; i < EPG * NH; i += 512) {
        int e = i >> 3, h = i & 7;
        esc[e][h] = expf(esc[e][h] - smx[dll[e]][h]) / (sden[dll[e]][h] + 1e-9f);
    }
    __syncthreads();
    for (int c = t; c < NPG * 64; c += 512) {
        int n = c >> 6, rem = c & 63, h = rem >> 3, d0 = (rem & 7) << 3;
        float a8[8] = {};
        for (int j = bstart[n]; j < bstart[n + 1]; j++) {
            int e = order[j];
            float a = esc[e][h];
            const float* zp = &zt[srcl[e]][h * 64 + d0];
#pragma unroll
            for (int q = 0; q < 8; q++) a8[q] = fmaf(a, zp[q], a8[q]);
        }
        ushort u[8];
#pragma unroll
        for (int q = 0; q < 8; q++) u[q] = f2bf(a8[q]);
        *(uint4*)&gnnB[((size_t)b * NPG + n) * HA + h * 64 + d0] = *(uint4*)u;
    }
}

extern "C" void kernel_launch(void* const* d_in, const int* in_sizes, int n_in,
                              void* d_out, int out_size, void* d_ws, size_t ws_size,
                              hipStream_t stream) {
    const float* locf  = (const float*)d_in[0];
    const float* gf    = (const float*)d_in[1];
    const int*   ei    = (const int*)d_in[2];
    const float* W1g   = (const float*)d_in[3];
    const float* b1g   = (const float*)d_in[4];
    const float* W2g   = (const float*)d_in[5];
    const float* b2g   = (const float*)d_in[6];
    const float* Wp    = (const float*)d_in[7];
    const float* bp    = (const float*)d_in[8];
    const float* Wg    = (const float*)d_in[9];
    const float* a_src = (const float*)d_in[10];
    const float* a_dst = (const float*)d_in[11];
    const float* Wllm  = (const float*)d_in[12];
    const float* bllm  = (const float*)d_in[13];
    float* out = (float*)d_out;
    float* ws  = (float*)d_ws;
    const int* es = ei;
    const int* ed = ei + NE;

    // d_out scratch layout (float offsets; every region dead before GEMM5 overwrite)
    ushort* W1gT   = (ushort*)(out + 8912896);          // dead after GEMM1
    ushort* hB     = (ushort*)(out + 8912896);          // overlaps W1gT, written GEMM3
    ushort* poolB  = (ushort*)(out + 34078720);
    float*  part1  = out + 40370176;                    // 16 x 512x2048 — dead after red1
    ushort* nodesB = (ushort*)(out + 40370176);         // overlaps dead part1
    ushort* g1B    = (ushort*)(out + 57147392);
    ushort* W2gT   = (ushort*)(out + 57671680);
    ushort* WpT    = (ushort*)(out + 58851328);
    ushort* WgT    = (ushort*)(out + 59441152);
    ushort* outgB  = (ushort*)(out + 59703296);
    float*  part2  = out + 59998208;                    // 4 x 512x1152 (ends 62.4M < 71.3M)
    // d_ws layout (GEMM5 inputs live here, never in d_out)
    ushort* WllmT = (ushort*)ws;
    ushort* gnnB  = (ushort*)(ws + 1048576);

    // fused transposes + pool
    k_prep<<<79744, 256, 0, stream>>>(W1g, W1gT, W2g, W2gT, Wp, WpT, Wg, WgT,
                                      Wllm, WllmT, gf, poolB);
    // GEMM1 (256sq 8-phase, split-K=16, z-major XCD order): -> f32 partials
    k_gemm256<true, true, false, false, false><<<dim3(8, 2, 16), 512, 0, stream>>>(
        poolB, W1gT, nullptr, part1, 512, GPD, C32, 1536);
    k_red<16, true><<<4096, 256, 0, stream>>>(part1, b1g, g1B, GPD, 1048576);
    // GEMM2 (128sq, split-K=4): [512,2048]x[2048,1152] -> partials; reduce + b2g
    k_gemm_bf<true, false, false, false><<<dim3(9, 4, 4), 256, 0, stream>>>(
        g1B, W2gT, nullptr, part2, 512, FEAT, GPD, 512);
    k_red<4, false><<<2304, 256, 0, stream>>>(part2, b2g, outgB, FEAT, 589824);
    // build node matrix
    k_nodes<<<9792, 256, 0, stream>>>(outgB, locf, nodesB);
    // GEMM3 (256sq): relu(nodes x Wp + bp) -> bf16 h [17408,1024]
    k_gemm256<false, false, true, true, true><<<dim3(4, 68), 512, 0, stream>>>(
        nodesB, WpT, bp, hB, NT, HID, FEAT, 0);
    // fused z-GEMM + graph attention -> bf16 gnn
    k_zgat<<<BB, 512, 0, stream>>>(es, ed, hB, WgT, a_src, a_dst, gnnB);
    // GEMM5 (256sq): out = gnn x Wllm + bllm -> f32 [17408,4096]
    k_gemm256<false, false, true, false, false><<<dim3(16, 68), 512, 0, stream>>>(
        gnnB, WllmT, bllm, out, NT, LLM, HA, 0);
}

// Round 7
// 575.659 us; speedup vs baseline: 1.1218x; 1.1218x over previous
//
#include <hip/hip_runtime.h>
#include <hip/hip_bf16.h>
#include <math.h>

#define BB    512
#define NPG   34
#define NT    17408
#define FEAT  1152
#define GPD   2048
#define HID   1024
#define NH    8
#define AD    64
#define HA    512
#define LLM   4096
#define EPG   272
#define NE    139264
#define C32   24576
#define CC    768

#define AS3 __attribute__((address_space(3)))
#define AS1 __attribute__((address_space(1)))

typedef __attribute__((ext_vector_type(8))) short short8v;
typedef __attribute__((ext_vector_type(4))) float f32x4;

__device__ __forceinline__ ushort f2bf(float f) {
    __hip_bfloat16 h = __float2bfloat16(f);
    return __builtin_bit_cast(ushort, h);
}

// ---------------- transpose body: W[R][Cn] -> bf16 WT[Cn][R] ----------------
__device__ __forceinline__ void d_transpose(const float* __restrict__ W, ushort* __restrict__ WT,
                                            int R, int Cn, int bx, int by,
                                            float (*tile)[33], int tid) {
    int c0 = bx * 32, r0 = by * 32;
    int tc = tid & 31, tr = tid >> 5;
#pragma unroll
    for (int i = 0; i < 4; i++)
        tile[tr + i * 8][tc] = W[(size_t)(r0 + tr + i * 8) * Cn + c0 + tc];
    __syncthreads();
#pragma unroll
    for (int it = 0; it < 2; it++) {
        int p = tid + it * 256;
        int c = p >> 4, pr = (p & 15) << 1;
        ushort2 v;
        v.x = f2bf(tile[pr][c]);
        v.y = f2bf(tile[pr + 1][c]);
        *(ushort2*)&WT[(size_t)(c0 + c) * R + r0 + pr] = v;
    }
}

// ---------------- pool body: [B,768,8,8,4] -> bf16 [B,24576] (2x2x2 mean) ----------------
__device__ __forceinline__ void d_pool(const float* __restrict__ gf, ushort* __restrict__ outB,
                                       int blk, int tid) {
    int t = blk * 256 + tid;
    int q = t & 15; int bc = t >> 4;
    int dO = q >> 2, hO = q & 3;
    const float* p = gf + (size_t)bc * 256 + dO * 64 + hO * 8;
    float4 r00 = *(const float4*)(p);
    float4 r01 = *(const float4*)(p + 4);
    float4 r10 = *(const float4*)(p + 32);
    float4 r11 = *(const float4*)(p + 36);
    float o0 = (r00.x + r00.y + r01.x + r01.y + r10.x + r10.y + r11.x + r11.y) * 0.125f;
    float o1 = (r00.z + r00.w + r01.z + r01.w + r10.z + r10.w + r11.z + r11.w) * 0.125f;
    int b = bc / CC, c = bc % CC;
    ushort2 v; v.x = f2bf(o0); v.y = f2bf(o1);
    *(ushort2*)(outB + (size_t)b * C32 + c * 32 + dO * 8 + hO * 2) = v;
}

// ---------------- fused prep: 5 weight transposes + pool, one launch ----------------
__global__ __launch_bounds__(256) void k_prep(
    const float* __restrict__ W1g, ushort* __restrict__ W1gT,
    const float* __restrict__ W2g, ushort* __restrict__ W2gT,
    const float* __restrict__ Wp,  ushort* __restrict__ WpT,
    const float* __restrict__ Wg,  ushort* __restrict__ WgT,
    const float* __restrict__ Wllm, ushort* __restrict__ WllmT,
    const float* __restrict__ gf,  ushort* __restrict__ poolB) {
    __shared__ float tile[32][33];
    int blk = blockIdx.x, tid = threadIdx.x;
    if (blk < 49152) {
        d_transpose(W1g, W1gT, C32, GPD, blk & 63, blk >> 6, tile, tid);
    } else if (blk < 51456) {
        int l = blk - 49152; d_transpose(W2g, W2gT, GPD, FEAT, l % 36, l / 36, tile, tid);
    } else if (blk < 52608) {
        int l = blk - 51456; d_transpose(Wp, WpT, FEAT, HID, l & 31, l >> 5, tile, tid);
    } else if (blk < 53120) {
        int l = blk - 52608; d_transpose(Wg, WgT, HID, HA, l & 15, l >> 4, tile, tid);
    } else if (blk < 55168) {
        int l = blk - 53120; d_transpose(Wllm, WllmT, HA, LLM, l & 127, l >> 7, tile, tid);
    } else {
        d_pool(gf, poolB, blk - 55168, tid);
    }
}

// ================= 256x256 8-phase bf16 MFMA GEMM (T2+T3+T4+T5) =================
// K-loop schedule identical to the round-4 verified template. Flat (y,x) XCD
// swizzle: with gx=8 the two y-blocks sharing a B-panel land on the SAME XCD.
#define GLDS(gp, lp) __builtin_amdgcn_global_load_lds((const AS1 void*)(gp), (AS3 void*)(lp), 16, 0, 0)
#define STAGE_A(buf, h, tt) { \
    const ushort* s_ = gAs + (size_t)(tt) * 64 + (size_t)(2 * (h)) * rK; \
    ushort* d_ = lds + (buf) * 32768 + (2 * (h)) * 4096 + (w << 9); \
    GLDS(s_, d_); GLDS(s_ + rK, d_ + 4096); }
#define STAGE_B(buf, h, tt) { \
    const ushort* s_ = gBs + (size_t)(tt) * 64 + (size_t)(2 * (h)) * rK; \
    ushort* d_ = lds + (buf) * 32768 + 16384 + (2 * (h)) * 4096 + (w << 9); \
    GLDS(s_, d_); GLDS(s_ + rK, d_ + 4096); }
#define DSRA(BO, mh) { _Pragma("unroll") for (int mf = 0; mf < 4; mf++) { \
    const ushort* p_ = lds + (BO) + aBase + ((mh) * 64 + mf * 16) * 64; \
    aF[mf][0] = *(const short8v*)(p_ + k0s); \
    aF[mf][1] = *(const short8v*)(p_ + k1s); } }
#define DSRB(BO, nh, BF) { _Pragma("unroll") for (int nf = 0; nf < 2; nf++) { \
    const ushort* p_ = lds + (BO) + bBase + ((nh) * 32 + nf * 16) * 64; \
    BF[nf][0] = *(const short8v*)(p_ + k0s); \
    BF[nf][1] = *(const short8v*)(p_ + k1s); } }
#define MM(mh, nh, BF) { \
    asm volatile("s_waitcnt lgkmcnt(0)" ::: "memory"); \
    __builtin_amdgcn_sched_barrier(0); \
    __builtin_amdgcn_s_setprio(1); \
    _Pragma("unroll") for (int mf = 0; mf < 4; mf++) \
    _Pragma("unroll") for (int nf = 0; nf < 2; nf++) { \
        acc[(mh)*4+mf][(nh)*2+nf] = __builtin_amdgcn_mfma_f32_16x16x32_bf16(aF[mf][0], BF[nf][0], acc[(mh)*4+mf][(nh)*2+nf], 0, 0, 0); \
        acc[(mh)*4+mf][(nh)*2+nf] = __builtin_amdgcn_mfma_f32_16x16x32_bf16(aF[mf][1], BF[nf][1], acc[(mh)*4+mf][(nh)*2+nf], 0, 0, 0); } \
    __builtin_amdgcn_s_setprio(0); }
#define BAR __builtin_amdgcn_s_barrier()
#define VMW4 { asm volatile("s_waitcnt vmcnt(4)" ::: "memory"); __builtin_amdgcn_sched_barrier(0); }

template<bool SPLITK, bool BIAS, bool RELU, bool OUTBF>
__global__ __launch_bounds__(512, 2) void k_gemm256(
    const ushort* __restrict__ A, const ushort* __restrict__ BT,
    const float* __restrict__ bias, void* __restrict__ Cout,
    int M, int N, int K, int kChunk) {
    __shared__ ushort lds[65536];            // 128 KiB: [buf][A 32KB | B 32KB]
    const int t = threadIdx.x;
    const int w = t >> 6, l = t & 63;
    const int wm = w >> 2, wn = w & 3;
    // bijective XCD swizzle over flattened (y,x); z (split-K) untouched
    const int gx = gridDim.x;
    const int nwg = gx * gridDim.y;
    const int id = blockIdx.y * gx + blockIdx.x;
    const int qx = nwg >> 3, rx = nwg & 7;
    const int xcd = id & 7, pos = id >> 3;
    const int nid = (xcd < rx ? xcd * (qx + 1) : rx * (qx + 1) + (xcd - rx) * qx) + pos;
    const int m0 = (nid / gx) * 256, n0 = (nid % gx) * 256;
    const int kBase = SPLITK ? blockIdx.z * kChunk : 0;
    const int NTt = (SPLITK ? kChunk : K) / 64;

    // staging source: linear LDS dest; inverse swizzle folded into global k-offset
    const int rowLo = t >> 3;
    const int keSrc = ((t & 7) << 3) ^ (((rowLo >> 2) & 1) << 5) ^ (((rowLo >> 3) & 1) << 4);
    const ushort* gAs = A + (size_t)(m0 + rowLo) * K + kBase + keSrc;
    const ushort* gBs = BT + (size_t)(n0 + rowLo) * K + kBase + keSrc;
    const size_t rK = (size_t)64 * K;

    // fragment read geometry (swizzled ds_read addresses)
    const int fcol = l & 15, fk = (l >> 4) << 3;
    const int flipR = (((l >> 2) & 1) << 5) | (((l >> 3) & 1) << 4);
    const int k0s = fk ^ flipR;
    const int k1s = fk ^ 32 ^ flipR;
    const int aBase = (wm * 128 + fcol) * 64;
    const int bBase = 16384 + (wn * 64 + fcol) * 64;

    short8v aF[4][2], bF0[2][2], bF1[2][2];
    f32x4 acc[8][4] = {};

    // prologue: tile0 {B0,B1,A0,A1} + tile1 {B0,B1}; confirm tile0
    STAGE_B(0, 0, 0); STAGE_B(0, 1, 0); STAGE_A(0, 0, 0); STAGE_A(0, 1, 0);
    STAGE_B(1, 0, 1); STAGE_B(1, 1, 1);
    VMW4;
    BAR;

    const int NITER = NTt >> 1;
    for (int it = 0; it < NITER; ++it) {
        const int t1 = 2 * it + 1;
        const int t2r = 2 * it + 2, t3r = 2 * it + 3;
        const int t2 = t2r < NTt ? t2r : 0;   // clamped dummies keep vmcnt uniform
        const int t3 = t3r < NTt ? t3r : 0;
        DSRA(0, 0); DSRB(0, 0, bF0); STAGE_A(1, 0, t1);
        BAR; MM(0, 0, bF0); BAR;
        DSRB(0, 1, bF1); STAGE_A(1, 1, t1);
        BAR; MM(0, 1, bF1); BAR;
        DSRA(0, 1); STAGE_B(0, 0, t2);
        BAR; MM(1, 1, bF1); BAR;
        STAGE_B(0, 1, t2); VMW4;
        BAR; MM(1, 0, bF0); BAR;
        DSRA(32768, 0); DSRB(32768, 0, bF0); STAGE_A(0, 0, t2);
        BAR; MM(0, 0, bF0); BAR;
        DSRB(32768, 1, bF1); STAGE_A(0, 1, t2);
        BAR; MM(0, 1, bF1); BAR;
        DSRA(32768, 1); STAGE_B(1, 0, t3);
        BAR; MM(1, 1, bF1); BAR;
        STAGE_B(1, 1, t3); VMW4;
        BAR; MM(1, 0, bF0); BAR;
    }
    asm volatile("s_waitcnt vmcnt(0)" ::: "memory");
    BAR;   // all waves drained their in-flight LDS writes before LDS reuse

    // ---- LDS-staged vectorized epilogue: 4 passes of 32 rows x 64 cols f32 ----
    const int orow = (l >> 4) << 2;
    float* eph = ((float*)lds) + w * 2176;   // wave-private 32x68 f32 (8.5 KB)
    const int ecol = (l & 15) << 2;
    const int erow4 = l >> 4;
#pragma unroll
    for (int pass = 0; pass < 4; pass++) {
#pragma unroll
        for (int mi = 0; mi < 2; mi++) {
            int mf = pass * 2 + mi;
#pragma unroll
            for (int nf = 0; nf < 4; nf++)
#pragma unroll
                for (int r = 0; r < 4; r++)
                    eph[(mi * 16 + orow + r) * 68 + nf * 16 + fcol] = acc[mf][nf][r];
        }
#pragma unroll
        for (int g = 0; g < 8; g++) {
            int lrow = g * 4 + erow4;
            f32x4 v = *(f32x4*)&eph[lrow * 68 + ecol];
            int row = m0 + wm * 128 + pass * 32 + lrow;
            int col = n0 + wn * 64 + ecol;
            if (BIAS) {
                float4 bb = *(const float4*)(bias + col);
                v[0] += bb.x; v[1] += bb.y; v[2] += bb.z; v[3] += bb.w;
            }
            if (RELU) {
#pragma unroll
                for (int q = 0; q < 4; q++) v[q] = v[q] > 0.f ? v[q] : 0.f;
            }
            if (OUTBF) {
                ushort4 u;
                u.x = f2bf(v[0]); u.y = f2bf(v[1]); u.z = f2bf(v[2]); u.w = f2bf(v[3]);
                *(ushort4*)&((ushort*)Cout)[(size_t)row * N + col] = u;
            } else {
                size_t off = (size_t)row * N + col;
                if (SPLITK) off += (size_t)blockIdx.z * (size_t)M * N;
                float4 fv = {v[0], v[1], v[2], v[3]};
                *(float4*)&((float*)Cout)[off] = fv;
            }
        }
    }
}

// ---------------- 128x128 m97-style bf16 GEMM (kept for GEMM2, N=1152) ----------------
template<bool SPLITK, bool BIAS, bool RELU, bool OUTBF>
__global__ __launch_bounds__(256) void k_gemm_bf(
    const ushort* __restrict__ A, const ushort* __restrict__ BT,
    const float* __restrict__ bias, void* __restrict__ Cout,
    int M, int N, int K, int kChunk) {
    __shared__ ushort lA[128 * 32];
    __shared__ ushort lB[128 * 32];
    const int t = threadIdx.x;
    const int w = t >> 6, l = t & 63;
    const int m0 = blockIdx.y * 128, n0 = blockIdx.x * 128;
    const int kLen = SPLITK ? kChunk : K;
    const int k0 = SPLITK ? blockIdx.z * kChunk : 0;
    const int srow = w * 16 + (l >> 2);
    const int skq = (l & 3) << 3;
    const ushort* gA = A + (size_t)(m0 + srow) * K + k0 + skq;
    const ushort* gB = BT + (size_t)(n0 + srow) * K + k0 + skq;
    ushort* lA0 = lA + w * 512;
    ushort* lB0 = lB + w * 512;
    const size_t str64 = (size_t)64 * K;
    const int wr = (w >> 1) << 6, wc = (w & 1) << 6;
    const int fcol = l & 15, fk = (l >> 4) << 3;

    f32x4 acc[4][4] = {};
    for (int kk = 0; kk < kLen; kk += 32) {
        __syncthreads();
        GLDS(gA + kk,         lA0);
        GLDS(gA + kk + str64, lA0 + 2048);
        GLDS(gB + kk,         lB0);
        GLDS(gB + kk + str64, lB0 + 2048);
        __syncthreads();
        short8v a[4], b[4];
#pragma unroll
        for (int f = 0; f < 4; f++) {
            a[f] = *(const short8v*)(lA + (wr + f * 16 + fcol) * 32 + fk);
            b[f] = *(const short8v*)(lB + (wc + f * 16 + fcol) * 32 + fk);
        }
#pragma unroll
        for (int i = 0; i < 4; i++)
#pragma unroll
            for (int j = 0; j < 4; j++)
                acc[i][j] = __builtin_amdgcn_mfma_f32_16x16x32_bf16(a[i], b[j], acc[i][j], 0, 0, 0);
    }
    const int orow = (l >> 4) << 2;
#pragma unroll
    for (int i = 0; i < 4; i++) {
#pragma unroll
        for (int j = 0; j < 4; j++) {
            int col = n0 + wc + j * 16 + fcol;
            float bv = BIAS ? bias[col] : 0.f;
#pragma unroll
            for (int r = 0; r < 4; r++) {
                int row = m0 + wr + i * 16 + orow + r;
                float v = acc[i][j][r] + bv;
                if (RELU) v = v > 0.f ? v : 0.f;
                if (OUTBF) {
                    ((ushort*)Cout)[(size_t)row * N + col] = f2bf(v);
                } else {
                    size_t off = (size_t)row * N + col;
                    if (SPLITK) off += (size_t)blockIdx.z * (size_t)M * N;
                    ((float*)Cout)[off] = v;
                }
            }
        }
    }
}

// ---------------- reduce split-K partials + bias (+relu) -> bf16 ----------------
template<int NP, bool RELU>
__global__ __launch_bounds__(256) void k_red(const float* __restrict__ part,
                                             const float* __restrict__ bias,
                                             ushort* __restrict__ outB,
                                             int N, int stride) {
    int i = blockIdx.x * 256 + threadIdx.x;
    float s = bias[i % N];
#pragma unroll
    for (int q = 0; q < NP; q++) s += part[i + (size_t)q * stride];
    if (RELU) s = s > 0.f ? s : 0.f;
    outB[i] = f2bf(s);
}

// ---------------- build bf16 node matrix [NT][FEAT] ----------------
__global__ __launch_bounds__(256) void k_nodes(const ushort* __restrict__ outgB,
                                               const float* __restrict__ locf,
                                               ushort* __restrict__ nodesB) {
    int idx = blockIdx.x * 256 + threadIdx.x;   // over NT*144 = 2,506,752 16B-chunks
    int node = idx / 144, cc = idx - node * 144;
    int b = node / NPG, j = node - b * NPG;
    int c = cc * 8;
    ushort* dst = nodesB + (size_t)node * FEAT + c;
    if (j == 0) {
        *(uint4*)dst = *(const uint4*)(outgB + (size_t)b * FEAT + c);
    } else {
        const float* s = locf + ((size_t)b * 33 + (j - 1)) * FEAT + c;
        float4 v0 = *(const float4*)s, v1 = *(const float4*)(s + 4);
        ushort u[8] = {f2bf(v0.x), f2bf(v0.y), f2bf(v0.z), f2bf(v0.w),
                       f2bf(v1.x), f2bf(v1.y), f2bf(v1.z), f2bf(v1.w)};
        *(uint4*)dst = *(uint4*)u;
    }
}

// ---------------- fused GAT: scores + per-graph softmax + aggregation ----------------
// one block per graph, 512 threads (LDS ~87KB caps at 1 block/CU; 8 waves hide latency).
// Per-element math and bucket order identical to the round-5 verified version.
__global__ __launch_bounds__(512) void k_gat(const int* __restrict__ es, const int* __restrict__ ed,
                                             const float* __restrict__ z,
                                             const float* __restrict__ a_src,
                                             const float* __restrict__ a_dst,
                                             ushort* __restrict__ gnnB) {
    __shared__ float zt[NPG][520];                   // padded rows (70.7 KB)
    __shared__ float sps[NPG][NH], spd[NPG][NH], sm[NPG][NH], sden[NPG][NH];
    __shared__ float esc[EPG][NH];
    __shared__ int srcl[EPG], dll[EPG], order[EPG], cnt[NPG], bstart[NPG + 1];
    int b = blockIdx.x, t = threadIdx.x;
    // stage z [34][512] f32 (coalesced float4)
    for (int i = t; i < NPG * 128; i += 512) {
        int n = i >> 7, c4 = (i & 127) << 2;
        *(float4*)&zt[n][c4] = *(const float4*)&z[((size_t)b * NPG + n) * HA + c4];
    }
    for (int e = t; e < EPG; e += 512) {
        srcl[e] = es[b * EPG + e] - b * NPG;
        dll[e]  = ed[b * EPG + e] - b * NPG;
    }
    if (t < NPG) cnt[t] = 0;
    __syncthreads();
    // scores: one wave per node (shuffle-reduced)
    {
        int wv = t >> 6, l = t & 63;
        for (int n = wv; n < NPG; n += 8) {
            float s[NH], d[NH];
#pragma unroll
            for (int i = 0; i < NH; i++) {
                float zv = zt[n][i * 64 + l];
                s[i] = zv * a_src[i * 64 + l];
                d[i] = zv * a_dst[i * 64 + l];
            }
#pragma unroll
            for (int i = 0; i < NH; i++) {
#pragma unroll
                for (int off = 32; off > 0; off >>= 1) {
                    s[i] += __shfl_xor(s[i], off);
                    d[i] += __shfl_xor(d[i], off);
                }
            }
            if (l == 0) {
#pragma unroll
                for (int i = 0; i < NH; i++) { sps[n][i] = s[i]; spd[n][i] = d[i]; }
            }
        }
    }
    for (int e = t; e < EPG; e += 512) atomicAdd(&cnt[dll[e]], 1);
    __syncthreads();
    if (t == 0) {   // deterministic serial prefix + scatter (ascending edge order)
        int s = 0;
        for (int n = 0; n < NPG; n++) { bstart[n] = s; s += cnt[n]; cnt[n] = bstart[n]; }
        bstart[NPG] = s;
        for (int e = 0; e < EPG; e++) order[cnt[dll[e]]++] = e;
    }
    __syncthreads();
    // edge scores (leaky relu)
    for (int i = t; i < EPG * NH; i += 512) {
        int e = i >> 3, h = i & 7;
        float sc = sps[srcl[e]][h] + spd[dll[e]][h];
        esc[e][h] = sc > 0.f ? sc : 0.2f * sc;
    }
    __syncthreads();
    // per-(node,head) max & denom over bucket (ascending edge order = bitwise stable)
    for (int i = t; i < NPG * NH; i += 512) {
        int n = i >> 3, h = i & 7;
        float m = -INFINITY;
        for (int j = bstart[n]; j < bstart[n + 1]; j++) m = fmaxf(m, esc[order[j]][h]);
        if (m == -INFINITY) m = 0.f;
        float den = 0.f;
        for (int j = bstart[n]; j < bstart[n + 1]; j++) den += expf(esc[order[j]][h] - m);
        sm[n][h] = m; sden[n][h] = den;
    }
    __syncthreads();
    // alpha in place
    for (int i = t; i < EPG * NH; i += 512) {
        int e = i >> 3, h = i & 7;
        esc[e][h] = expf(esc[e][h] - sm[dll[e]][h]) / (sden[dll[e]][h] + 1e-9f);
    }
    __syncthreads();
    // aggregation: thread handles (n, h, 8-wide d chunk) -> coalesced uint4 bf16 store
    for (int c = t; c < NPG * 64; c += 512) {
        int n = c >> 6, rem = c & 63, h = rem >> 3, d0 = (rem & 7) << 3;
        float acc[8] = {};
        for (int j = bstart[n]; j < bstart[n + 1]; j++) {
            int e = order[j];
            float a = esc[e][h];
            const float* zp = &zt[srcl[e]][h * 64 + d0];
#pragma unroll
            for (int q = 0; q < 8; q++) acc[q] = fmaf(a, zp[q], acc[q]);
        }
        ushort u[8];
#pragma unroll
        for (int q = 0; q < 8; q++) u[q] = f2bf(acc[q]);
        *(uint4*)&gnnB[((size_t)b * NPG + n) * HA + h * 64 + d0] = *(uint4*)u;
    }
}

extern "C" void kernel_launch(void* const* d_in, const int* in_sizes, int n_in,
                              void* d_out, int out_size, void* d_ws, size_t ws_size,
                              hipStream_t stream) {
    const float* locf  = (const float*)d_in[0];
    const float* gf    = (const float*)d_in[1];
    const int*   ei    = (const int*)d_in[2];
    const float* W1g   = (const float*)d_in[3];
    const float* b1g   = (const float*)d_in[4];
    const float* W2g   = (const float*)d_in[5];
    const float* b2g   = (const float*)d_in[6];
    const float* Wp    = (const float*)d_in[7];
    const float* bp    = (const float*)d_in[8];
    const float* Wg    = (const float*)d_in[9];
    const float* a_src = (const float*)d_in[10];
    const float* a_dst = (const float*)d_in[11];
    const float* Wllm  = (const float*)d_in[12];
    const float* bllm  = (const float*)d_in[13];
    float* out = (float*)d_out;
    float* ws  = (float*)d_ws;
    const int* es = ei;
    const int* ed = ei + NE;

    // d_out scratch layout (float offsets; every region dead before GEMM5 overwrite)
    float*  z      = out;                               // [0, 8,912,896)
    ushort* W1gT   = (ushort*)(out + 8912896);          // dead after GEMM1
    ushort* hB     = (ushort*)(out + 8912896);          // overlaps W1gT, written GEMM3
    ushort* poolB  = (ushort*)(out + 34078720);
    float*  part1  = out + 40370176;                    // 16 x 512x2048 — dead after red1
    ushort* nodesB = (ushort*)(out + 40370176);         // overlaps dead part1
    ushort* g1B    = (ushort*)(out + 57147392);
    ushort* W2gT   = (ushort*)(out + 57671680);
    ushort* WpT    = (ushort*)(out + 58851328);
    ushort* WgT    = (ushort*)(out + 59441152);
    ushort* outgB  = (ushort*)(out + 59703296);
    float*  part2  = out + 59998208;                    // 4 x 512x1152 (ends 62.4M < 71.3M)
    // d_ws layout (GEMM5 inputs live here, never in d_out)
    ushort* WllmT = (ushort*)ws;
    ushort* gnnB  = (ushort*)(ws + 1048576);

    // fused transposes + pool
    k_prep<<<79744, 256, 0, stream>>>(W1g, W1gT, W2g, W2gT, Wp, WpT, Wg, WgT,
                                      Wllm, WllmT, gf, poolB);
    // GEMM1 (256sq 8-phase, split-K=16): [512,24576]x[24576,2048] -> f32 partials
    k_gemm256<true, false, false, false><<<dim3(8, 2, 16), 512, 0, stream>>>(
        poolB, W1gT, nullptr, part1, 512, GPD, C32, 1536);
    k_red<16, true><<<4096, 256, 0, stream>>>(part1, b1g, g1B, GPD, 1048576);
    // GEMM2 (128sq, split-K=4): [512,2048]x[2048,1152] -> partials; reduce + b2g
    k_gemm_bf<true, false, false, false><<<dim3(9, 4, 4), 256, 0, stream>>>(
        g1B, W2gT, nullptr, part2, 512, FEAT, GPD, 512);
    k_red<4, false><<<2304, 256, 0, stream>>>(part2, b2g, outgB, FEAT, 589824);
    // build node matrix
    k_nodes<<<9792, 256, 0, stream>>>(outgB, locf, nodesB);
    // GEMM3 (256sq): relu(nodes x Wp + bp) -> bf16 h [17408,1024]
    k_gemm256<false, true, true, true><<<dim3(4, 68), 512, 0, stream>>>(
        nodesB, WpT, bp, hB, NT, HID, FEAT, 0);
    // GEMM4 (256sq): z = h x Wg -> f32 [17408,512]
    k_gemm256<false, false, false, false><<<dim3(2, 68), 512, 0, stream>>>(
        hB, WgT, nullptr, z, NT, HA, HID, 0);
    // fused graph attention (512 threads)
    k_gat<<<BB, 512, 0, stream>>>(es, ed, z, a_src, a_dst, gnnB);
    // GEMM5 (256sq): out = gnn x Wllm + bllm -> f32 [17408,4096]
    k_gemm256<false, true, false, false><<<dim3(16, 68), 512, 0, stream>>>(
        gnnB, WllmT, bllm, out, NT, LLM, HA, 0);
}

// Round 8
// 554.349 us; speedup vs baseline: 1.1649x; 1.0384x over previous
//
#include <hip/hip_runtime.h>
#include <hip/hip_bf16.h>
#include <math.h>

#define BB    512
#define NPG   34
#define NT    17408
#define FEAT  1152
#define GPD   2048
#define HID   1024
#define NH    8
#define AD    64
#define HA    512
#define LLM   4096
#define EPG   272
#define NE    139264
#define C32   24576
#define CC    768

#define AS3 __attribute__((address_space(3)))
#define AS1 __attribute__((address_space(1)))

typedef __attribute__((ext_vector_type(8))) short short8v;
typedef __attribute__((ext_vector_type(4))) float f32x4;

__device__ __forceinline__ ushort f2bf(float f) {
    __hip_bfloat16 h = __float2bfloat16(f);
    return __builtin_bit_cast(ushort, h);
}
__device__ __forceinline__ float bf2f(ushort u) {
    unsigned int x = ((unsigned int)u) << 16;
    return __builtin_bit_cast(float, x);
}

// ---------------- 64x64 transpose body: W[R][Cn] -> bf16 WT[Cn][R], 16B writes ----------------
__device__ __forceinline__ void d_transpose64(const float* __restrict__ W, ushort* __restrict__ WT,
                                              int R, int Cn, int bx, int by,
                                              float (*tile)[65], int tid) {
    int c0 = bx * 64, r0 = by * 64;
    int rc = tid >> 6, cc = tid & 63;
#pragma unroll
    for (int i = 0; i < 16; i++) {
        int r = i * 4 + rc;
        tile[r][cc] = W[(size_t)(r0 + r) * Cn + c0 + cc];
    }
    __syncthreads();
#pragma unroll
    for (int i = 0; i < 2; i++) {
        int p = tid + i * 256;
        int c = p >> 3, ro = (p & 7) << 3;
        ushort u[8];
#pragma unroll
        for (int k = 0; k < 8; k++) u[k] = f2bf(tile[ro + k][c]);
        *(uint4*)&WT[(size_t)(c0 + c) * R + r0 + ro] = *(uint4*)u;
    }
}

// ---------------- pool body: [B,768,8,8,4] -> bf16 [B,24576] (2x2x2 mean) ----------------
__device__ __forceinline__ void d_pool(const float* __restrict__ gf, ushort* __restrict__ outB,
                                       int blk, int tid) {
    int t = blk * 256 + tid;
    int q = t & 15; int bc = t >> 4;
    int dO = q >> 2, hO = q & 3;
    const float* p = gf + (size_t)bc * 256 + dO * 64 + hO * 8;
    float4 r00 = *(const float4*)(p);
    float4 r01 = *(const float4*)(p + 4);
    float4 r10 = *(const float4*)(p + 32);
    float4 r11 = *(const float4*)(p + 36);
    float o0 = (r00.x + r00.y + r01.x + r01.y + r10.x + r10.y + r11.x + r11.y) * 0.125f;
    float o1 = (r00.z + r00.w + r01.z + r01.w + r10.z + r10.w + r11.z + r11.w) * 0.125f;
    int b = bc / CC, c = bc % CC;
    ushort2 v; v.x = f2bf(o0); v.y = f2bf(o1);
    *(ushort2*)(outB + (size_t)b * C32 + c * 32 + dO * 8 + hO * 2) = v;
}

// ---------------- fused prep: 5 weight transposes (64x64) + pool, one launch ----------------
// ranges: [0,12288) W1g | [12288,12864) W2g | [12864,13152) Wp | [13152,13280) Wg
//         [13280,13792) Wllm | [13792,38368) pool
__global__ __launch_bounds__(256) void k_prep(
    const float* __restrict__ W1g, ushort* __restrict__ W1gT,
    const float* __restrict__ W2g, ushort* __restrict__ W2gT,
    const float* __restrict__ Wp,  ushort* __restrict__ WpT,
    const float* __restrict__ Wg,  ushort* __restrict__ WgT,
    const float* __restrict__ Wllm, ushort* __restrict__ WllmT,
    const float* __restrict__ gf,  ushort* __restrict__ poolB) {
    __shared__ float tile[64][65];
    int blk = blockIdx.x, tid = threadIdx.x;
    if (blk < 12288) {
        d_transpose64(W1g, W1gT, C32, GPD, blk & 31, blk >> 5, tile, tid);
    } else if (blk < 12864) {
        int l = blk - 12288; d_transpose64(W2g, W2gT, GPD, FEAT, l % 18, l / 18, tile, tid);
    } else if (blk < 13152) {
        int l = blk - 12864; d_transpose64(Wp, WpT, FEAT, HID, l & 15, l >> 4, tile, tid);
    } else if (blk < 13280) {
        int l = blk - 13152; d_transpose64(Wg, WgT, HID, HA, l & 7, l >> 3, tile, tid);
    } else if (blk < 13792) {
        int l = blk - 13280; d_transpose64(Wllm, WllmT, HA, LLM, l & 63, l >> 6, tile, tid);
    } else {
        d_pool(gf, poolB, blk - 13792, tid);
    }
}

// ================= 256x256 8-phase bf16 MFMA GEMM (T2+T3+T4+T5) =================
// K-loop schedule identical to the round-4 verified template. Flat (y,x) XCD
// swizzle: with gx=8 the two y-blocks sharing a B-panel land on the SAME XCD.
#define GLDS(gp, lp) __builtin_amdgcn_global_load_lds((const AS1 void*)(gp), (AS3 void*)(lp), 16, 0, 0)
#define STAGE_A(buf, h, tt) { \
    const ushort* s_ = gAs + (size_t)(tt) * 64 + (size_t)(2 * (h)) * rK; \
    ushort* d_ = lds + (buf) * 32768 + (2 * (h)) * 4096 + (w << 9); \
    GLDS(s_, d_); GLDS(s_ + rK, d_ + 4096); }
#define STAGE_B(buf, h, tt) { \
    const ushort* s_ = gBs + (size_t)(tt) * 64 + (size_t)(2 * (h)) * rK; \
    ushort* d_ = lds + (buf) * 32768 + 16384 + (2 * (h)) * 4096 + (w << 9); \
    GLDS(s_, d_); GLDS(s_ + rK, d_ + 4096); }
#define DSRA(BO, mh) { _Pragma("unroll") for (int mf = 0; mf < 4; mf++) { \
    const ushort* p_ = lds + (BO) + aBase + ((mh) * 64 + mf * 16) * 64; \
    aF[mf][0] = *(const short8v*)(p_ + k0s); \
    aF[mf][1] = *(const short8v*)(p_ + k1s); } }
#define DSRB(BO, nh, BF) { _Pragma("unroll") for (int nf = 0; nf < 2; nf++) { \
    const ushort* p_ = lds + (BO) + bBase + ((nh) * 32 + nf * 16) * 64; \
    BF[nf][0] = *(const short8v*)(p_ + k0s); \
    BF[nf][1] = *(const short8v*)(p_ + k1s); } }
#define MM(mh, nh, BF) { \
    asm volatile("s_waitcnt lgkmcnt(0)" ::: "memory"); \
    __builtin_amdgcn_sched_barrier(0); \
    __builtin_amdgcn_s_setprio(1); \
    _Pragma("unroll") for (int mf = 0; mf < 4; mf++) \
    _Pragma("unroll") for (int nf = 0; nf < 2; nf++) { \
        acc[(mh)*4+mf][(nh)*2+nf] = __builtin_amdgcn_mfma_f32_16x16x32_bf16(aF[mf][0], BF[nf][0], acc[(mh)*4+mf][(nh)*2+nf], 0, 0, 0); \
        acc[(mh)*4+mf][(nh)*2+nf] = __builtin_amdgcn_mfma_f32_16x16x32_bf16(aF[mf][1], BF[nf][1], acc[(mh)*4+mf][(nh)*2+nf], 0, 0, 0); } \
    __builtin_amdgcn_s_setprio(0); }
#define BAR __builtin_amdgcn_s_barrier()
#define VMW4 { asm volatile("s_waitcnt vmcnt(4)" ::: "memory"); __builtin_amdgcn_sched_barrier(0); }

template<bool SPLITK, bool BIAS, bool RELU, bool OUTBF>
__global__ __launch_bounds__(512, 2) void k_gemm256(
    const ushort* __restrict__ A, const ushort* __restrict__ BT,
    const float* __restrict__ bias, void* __restrict__ Cout,
    int M, int N, int K, int kChunk) {
    __shared__ ushort lds[65536];            // 128 KiB: [buf][A 32KB | B 32KB]
    const int t = threadIdx.x;
    const int w = t >> 6, l = t & 63;
    const int wm = w >> 2, wn = w & 3;
    // bijective XCD swizzle over flattened (y,x); z (split-K) untouched
    const int gx = gridDim.x;
    const int nwg = gx * gridDim.y;
    const int id = blockIdx.y * gx + blockIdx.x;
    const int qx = nwg >> 3, rx = nwg & 7;
    const int xcd = id & 7, pos = id >> 3;
    const int nid = (xcd < rx ? xcd * (qx + 1) : rx * (qx + 1) + (xcd - rx) * qx) + pos;
    const int m0 = (nid / gx) * 256, n0 = (nid % gx) * 256;
    const int kBase = SPLITK ? blockIdx.z * kChunk : 0;
    const int NTt = (SPLITK ? kChunk : K) / 64;

    // staging source: linear LDS dest; inverse swizzle folded into global k-offset
    const int rowLo = t >> 3;
    const int keSrc = ((t & 7) << 3) ^ (((rowLo >> 2) & 1) << 5) ^ (((rowLo >> 3) & 1) << 4);
    const ushort* gAs = A + (size_t)(m0 + rowLo) * K + kBase + keSrc;
    const ushort* gBs = BT + (size_t)(n0 + rowLo) * K + kBase + keSrc;
    const size_t rK = (size_t)64 * K;

    // fragment read geometry (swizzled ds_read addresses)
    const int fcol = l & 15, fk = (l >> 4) << 3;
    const int flipR = (((l >> 2) & 1) << 5) | (((l >> 3) & 1) << 4);
    const int k0s = fk ^ flipR;
    const int k1s = fk ^ 32 ^ flipR;
    const int aBase = (wm * 128 + fcol) * 64;
    const int bBase = 16384 + (wn * 64 + fcol) * 64;

    short8v aF[4][2], bF0[2][2], bF1[2][2];
    f32x4 acc[8][4] = {};

    // prologue: tile0 {B0,B1,A0,A1} + tile1 {B0,B1}; confirm tile0
    STAGE_B(0, 0, 0); STAGE_B(0, 1, 0); STAGE_A(0, 0, 0); STAGE_A(0, 1, 0);
    STAGE_B(1, 0, 1); STAGE_B(1, 1, 1);
    VMW4;
    BAR;

    const int NITER = NTt >> 1;
    for (int it = 0; it < NITER; ++it) {
        const int t1 = 2 * it + 1;
        const int t2r = 2 * it + 2, t3r = 2 * it + 3;
        const int t2 = t2r < NTt ? t2r : 0;   // clamped dummies keep vmcnt uniform
        const int t3 = t3r < NTt ? t3r : 0;
        DSRA(0, 0); DSRB(0, 0, bF0); STAGE_A(1, 0, t1);
        BAR; MM(0, 0, bF0); BAR;
        DSRB(0, 1, bF1); STAGE_A(1, 1, t1);
        BAR; MM(0, 1, bF1); BAR;
        DSRA(0, 1); STAGE_B(0, 0, t2);
        BAR; MM(1, 1, bF1); BAR;
        STAGE_B(0, 1, t2); VMW4;
        BAR; MM(1, 0, bF0); BAR;
        DSRA(32768, 0); DSRB(32768, 0, bF0); STAGE_A(0, 0, t2);
        BAR; MM(0, 0, bF0); BAR;
        DSRB(32768, 1, bF1); STAGE_A(0, 1, t2);
        BAR; MM(0, 1, bF1); BAR;
        DSRA(32768, 1); STAGE_B(1, 0, t3);
        BAR; MM(1, 1, bF1); BAR;
        STAGE_B(1, 1, t3); VMW4;
        BAR; MM(1, 0, bF0); BAR;
    }
    asm volatile("s_waitcnt vmcnt(0)" ::: "memory");
    BAR;   // all waves drained their in-flight LDS writes before LDS reuse

    // ---- LDS-staged vectorized epilogue: 4 passes of 32 rows x 64 cols f32 ----
    const int orow = (l >> 4) << 2;
    float* eph = ((float*)lds) + w * 2176;   // wave-private 32x68 f32 (8.5 KB)
    const int ecol = (l & 15) << 2;
    const int erow4 = l >> 4;
#pragma unroll
    for (int pass = 0; pass < 4; pass++) {
#pragma unroll
        for (int mi = 0; mi < 2; mi++) {
            int mf = pass * 2 + mi;
#pragma unroll
            for (int nf = 0; nf < 4; nf++)
#pragma unroll
                for (int r = 0; r < 4; r++)
                    eph[(mi * 16 + orow + r) * 68 + nf * 16 + fcol] = acc[mf][nf][r];
        }
#pragma unroll
        for (int g = 0; g < 8; g++) {
            int lrow = g * 4 + erow4;
            f32x4 v = *(f32x4*)&eph[lrow * 68 + ecol];
            int row = m0 + wm * 128 + pass * 32 + lrow;
            int col = n0 + wn * 64 + ecol;
            if (BIAS) {
                float4 bb = *(const float4*)(bias + col);
                v[0] += bb.x; v[1] += bb.y; v[2] += bb.z; v[3] += bb.w;
            }
            if (RELU) {
#pragma unroll
                for (int q = 0; q < 4; q++) v[q] = v[q] > 0.f ? v[q] : 0.f;
            }
            size_t off = (size_t)row * N + col;
            if (SPLITK) off += (size_t)blockIdx.z * (size_t)M * N;
            if (OUTBF) {
                ushort4 u;
                u.x = f2bf(v[0]); u.y = f2bf(v[1]); u.z = f2bf(v[2]); u.w = f2bf(v[3]);
                *(ushort4*)&((ushort*)Cout)[off] = u;
            } else {
                float4 fv = {v[0], v[1], v[2], v[3]};
                *(float4*)&((float*)Cout)[off] = fv;
            }
        }
    }
}

// ---------------- 128x128 m97-style bf16 GEMM (kept for GEMM2, N=1152) ----------------
template<bool SPLITK, bool BIAS, bool RELU, bool OUTBF>
__global__ __launch_bounds__(256) void k_gemm_bf(
    const ushort* __restrict__ A, const ushort* __restrict__ BT,
    const float* __restrict__ bias, void* __restrict__ Cout,
    int M, int N, int K, int kChunk) {
    __shared__ ushort lA[128 * 32];
    __shared__ ushort lB[128 * 32];
    const int t = threadIdx.x;
    const int w = t >> 6, l = t & 63;
    const int m0 = blockIdx.y * 128, n0 = blockIdx.x * 128;
    const int kLen = SPLITK ? kChunk : K;
    const int k0 = SPLITK ? blockIdx.z * kChunk : 0;
    const int srow = w * 16 + (l >> 2);
    const int skq = (l & 3) << 3;
    const ushort* gA = A + (size_t)(m0 + srow) * K + k0 + skq;
    const ushort* gB = BT + (size_t)(n0 + srow) * K + k0 + skq;
    ushort* lA0 = lA + w * 512;
    ushort* lB0 = lB + w * 512;
    const size_t str64 = (size_t)64 * K;
    const int wr = (w >> 1) << 6, wc = (w & 1) << 6;
    const int fcol = l & 15, fk = (l >> 4) << 3;

    f32x4 acc[4][4] = {};
    for (int kk = 0; kk < kLen; kk += 32) {
        __syncthreads();
        GLDS(gA + kk,         lA0);
        GLDS(gA + kk + str64, lA0 + 2048);
        GLDS(gB + kk,         lB0);
        GLDS(gB + kk + str64, lB0 + 2048);
        __syncthreads();
        short8v a[4], b[4];
#pragma unroll
        for (int f = 0; f < 4; f++) {
            a[f] = *(const short8v*)(lA + (wr + f * 16 + fcol) * 32 + fk);
            b[f] = *(const short8v*)(lB + (wc + f * 16 + fcol) * 32 + fk);
        }
#pragma unroll
        for (int i = 0; i < 4; i++)
#pragma unroll
            for (int j = 0; j < 4; j++)
                acc[i][j] = __builtin_amdgcn_mfma_f32_16x16x32_bf16(a[i], b[j], acc[i][j], 0, 0, 0);
    }
    const int orow = (l >> 4) << 2;
#pragma unroll
    for (int i = 0; i < 4; i++) {
#pragma unroll
        for (int j = 0; j < 4; j++) {
            int col = n0 + wc + j * 16 + fcol;
            float bv = BIAS ? bias[col] : 0.f;
#pragma unroll
            for (int r = 0; r < 4; r++) {
                int row = m0 + wr + i * 16 + orow + r;
                float v = acc[i][j][r] + bv;
                if (RELU) v = v > 0.f ? v : 0.f;
                if (OUTBF) {
                    ((ushort*)Cout)[(size_t)row * N + col] = f2bf(v);
                } else {
                    size_t off = (size_t)row * N + col;
                    if (SPLITK) off += (size_t)blockIdx.z * (size_t)M * N;
                    ((float*)Cout)[off] = v;
                }
            }
        }
    }
}

// ---------------- reduce GEMM1 bf16 partials + b1g + relu -> bf16 g1 (8 elems/thread) ----------------
__global__ __launch_bounds__(256) void k_red1(const ushort* __restrict__ part,
                                              const float* __restrict__ b1g,
                                              ushort* __restrict__ g1B) {
    int i8 = (blockIdx.x * 256 + threadIdx.x) * 8;   // over 512*2048
    float v[8];
#pragma unroll
    for (int k = 0; k < 8; k++) v[k] = b1g[(i8 + k) & (GPD - 1)];
#pragma unroll
    for (int q = 0; q < 16; q++) {
        uint4 pk = *(const uint4*)(part + (size_t)q * 1048576 + i8);
        const ushort* pu = (const ushort*)&pk;
#pragma unroll
        for (int k = 0; k < 8; k++) v[k] += bf2f(pu[k]);
    }
    ushort u[8];
#pragma unroll
    for (int k = 0; k < 8; k++) u[k] = f2bf(v[k] > 0.f ? v[k] : 0.f);
    *(uint4*)&g1B[i8] = *(uint4*)u;
}

// ---------------- build bf16 node matrix [NT][FEAT]; fused red2 for global rows ----------------
__global__ __launch_bounds__(256) void k_nodes(const float* __restrict__ part2,
                                               const float* __restrict__ b2g,
                                               const float* __restrict__ locf,
                                               ushort* __restrict__ nodesB) {
    int idx = blockIdx.x * 256 + threadIdx.x;   // over NT*144 = 2,506,752 16B-chunks
    int node = idx / 144, cc = idx - node * 144;
    int b = node / NPG, j = node - b * NPG;
    int c = cc * 8;
    ushort* dst = nodesB + (size_t)node * FEAT + c;
    if (j == 0) {
        // fused red2: bias + 4 split-K partials (ascending, same order as k_red)
        float v[8];
        float4 b0 = *(const float4*)(b2g + c), b1 = *(const float4*)(b2g + c + 4);
        v[0] = b0.x; v[1] = b0.y; v[2] = b0.z; v[3] = b0.w;
        v[4] = b1.x; v[5] = b1.y; v[6] = b1.z; v[7] = b1.w;
#pragma unroll
        for (int q = 0; q < 4; q++) {
            const float* pp = part2 + (size_t)q * 589824 + (size_t)b * FEAT + c;
            float4 p0 = *(const float4*)pp, p1 = *(const float4*)(pp + 4);
            v[0] += p0.x; v[1] += p0.y; v[2] += p0.z; v[3] += p0.w;
            v[4] += p1.x; v[5] += p1.y; v[6] += p1.z; v[7] += p1.w;
        }
        ushort u[8];
#pragma unroll
        for (int k = 0; k < 8; k++) u[k] = f2bf(v[k]);
        *(uint4*)dst = *(uint4*)u;
    } else {
        const float* s = locf + ((size_t)b * 33 + (j - 1)) * FEAT + c;
        float4 v0 = *(const float4*)s, v1 = *(const float4*)(s + 4);
        ushort u[8] = {f2bf(v0.x), f2bf(v0.y), f2bf(v0.z), f2bf(v0.w),
                       f2bf(v1.x), f2bf(v1.y), f2bf(v1.z), f2bf(v1.w)};
        *(uint4*)dst = *(uint4*)u;
    }
}

// ---------------- fused GAT: scores + per-graph softmax + aggregation ----------------
// one block per graph, 512 threads; math and bucket order identical to round-5/7 verified
__global__ __launch_bounds__(512) void k_gat(const int* __restrict__ es, const int* __restrict__ ed,
                                             const float* __restrict__ z,
                                             const float* __restrict__ a_src,
                                             const float* __restrict__ a_dst,
                                             ushort* __restrict__ gnnB) {
    __shared__ float zt[NPG][520];                   // padded rows (70.7 KB)
    __shared__ float sps[NPG][NH], spd[NPG][NH], sm[NPG][NH], sden[NPG][NH];
    __shared__ float esc[EPG][NH];
    __shared__ int srcl[EPG], dll[EPG], order[EPG], cnt[NPG], bstart[NPG + 1];
    int b = blockIdx.x, t = threadIdx.x;
    for (int i = t; i < NPG * 128; i += 512) {
        int n = i >> 7, c4 = (i & 127) << 2;
        *(float4*)&zt[n][c4] = *(const float4*)&z[((size_t)b * NPG + n) * HA + c4];
    }
    for (int e = t; e < EPG; e += 512) {
        srcl[e] = es[b * EPG + e] - b * NPG;
        dll[e]  = ed[b * EPG + e] - b * NPG;
    }
    if (t < NPG) cnt[t] = 0;
    __syncthreads();
    {
        int wv = t >> 6, l = t & 63;
        for (int n = wv; n < NPG; n += 8) {
            float s[NH], d[NH];
#pragma unroll
            for (int i = 0; i < NH; i++) {
                float zv = zt[n][i * 64 + l];
                s[i] = zv * a_src[i * 64 + l];
                d[i] = zv * a_dst[i * 64 + l];
            }
#pragma unroll
            for (int i = 0; i < NH; i++) {
#pragma unroll
                for (int off = 32; off > 0; off >>= 1) {
                    s[i] += __shfl_xor(s[i], off);
                    d[i] += __shfl_xor(d[i], off);
                }
            }
            if (l == 0) {
#pragma unroll
                for (int i = 0; i < NH; i++) { sps[n][i] = s[i]; spd[n][i] = d[i]; }
            }
        }
    }
    for (int e = t; e < EPG; e += 512) atomicAdd(&cnt[dll[e]], 1);
    __syncthreads();
    if (t == 0) {   // deterministic serial prefix + scatter (ascending edge order)
        int s = 0;
        for (int n = 0; n < NPG; n++) { bstart[n] = s; s += cnt[n]; cnt[n] = bstart[n]; }
        bstart[NPG] = s;
        for (int e = 0; e < EPG; e++) order[cnt[dll[e]]++] = e;
    }
    __syncthreads();
    for (int i = t; i < EPG * NH; i += 512) {
        int e = i >> 3, h = i & 7;
        float sc = sps[srcl[e]][h] + spd[dll[e]][h];
        esc[e][h] = sc > 0.f ? sc : 0.2f * sc;
    }
    __syncthreads();
    for (int i = t; i < NPG * NH; i += 512) {
        int n = i >> 3, h = i & 7;
        float m = -INFINITY;
        for (int j = bstart[n]; j < bstart[n + 1]; j++) m = fmaxf(m, esc[order[j]][h]);
        if (m == -INFINITY) m = 0.f;
        float den = 0.f;
        for (int j = bstart[n]; j < bstart[n + 1]; j++) den += expf(esc[order[j]][h] - m);
        sm[n][h] = m; sden[n][h] = den;
    }
    __syncthreads();
    for (int i = t; i < EPG * NH; i += 512) {
        int e = i >> 3, h = i & 7;
        esc[e][h] = expf(esc[e][h] - sm[dll[e]][h]) / (sden[dll[e]][h] + 1e-9f);
    }
    __syncthreads();
    for (int c = t; c < NPG * 64; c += 512) {
        int n = c >> 6, rem = c & 63, h = rem >> 3, d0 = (rem & 7) << 3;
        float acc[8] = {};
        for (int j = bstart[n]; j < bstart[n + 1]; j++) {
            int e = order[j];
            float a = esc[e][h];
            const float* zp = &zt[srcl[e]][h * 64 + d0];
#pragma unroll
            for (int q = 0; q < 8; q++) acc[q] = fmaf(a, zp[q], acc[q]);
        }
        ushort u[8];
#pragma unroll
        for (int q = 0; q < 8; q++) u[q] = f2bf(acc[q]);
        *(uint4*)&gnnB[((size_t)b * NPG + n) * HA + h * 64 + d0] = *(uint4*)u;
    }
}

extern "C" void kernel_launch(void* const* d_in, const int* in_sizes, int n_in,
                              void* d_out, int out_size, void* d_ws, size_t ws_size,
                              hipStream_t stream) {
    const float* locf  = (const float*)d_in[0];
    const float* gf    = (const float*)d_in[1];
    const int*   ei    = (const int*)d_in[2];
    const float* W1g   = (const float*)d_in[3];
    const float* b1g   = (const float*)d_in[4];
    const float* W2g   = (const float*)d_in[5];
    const float* b2g   = (const float*)d_in[6];
    const float* Wp    = (const float*)d_in[7];
    const float* bp    = (const float*)d_in[8];
    const float* Wg    = (const float*)d_in[9];
    const float* a_src = (const float*)d_in[10];
    const float* a_dst = (const float*)d_in[11];
    const float* Wllm  = (const float*)d_in[12];
    const float* bllm  = (const float*)d_in[13];
    float* out = (float*)d_out;
    float* ws  = (float*)d_ws;
    const int* es = ei;
    const int* ed = ei + NE;

    // d_out scratch layout (float offsets; every region dead before GEMM5 overwrite)
    float*  z      = out;                               // [0, 8,912,896)
    ushort* W1gT   = (ushort*)(out + 8912896);          // dead after GEMM1
    ushort* hB     = (ushort*)(out + 8912896);          // overlaps W1gT, written GEMM3
    ushort* poolB  = (ushort*)(out + 34078720);
    ushort* part1B = (ushort*)(out + 40370176);         // 16 x 512x2048 bf16 — dead after red1
    ushort* nodesB = (ushort*)(out + 40370176);         // overlaps dead part1B
    ushort* g1B    = (ushort*)(out + 57147392);
    ushort* W2gT   = (ushort*)(out + 57671680);
    ushort* WpT    = (ushort*)(out + 58851328);
    ushort* WgT    = (ushort*)(out + 59441152);
    float*  part2  = out + 59998208;                    // 4 x 512x1152 f32 (ends 62.4M < 71.3M)
    // d_ws layout (GEMM5 inputs live here, never in d_out)
    ushort* WllmT = (ushort*)ws;
    ushort* gnnB  = (ushort*)(ws + 1048576);

    // fused transposes (64x64, 16B writes) + pool
    k_prep<<<38368, 256, 0, stream>>>(W1g, W1gT, W2g, W2gT, Wp, WpT, Wg, WgT,
                                      Wllm, WllmT, gf, poolB);
    // GEMM1 (256sq 8-phase, split-K=16): [512,24576]x[24576,2048] -> bf16 partials
    k_gemm256<true, false, false, true><<<dim3(8, 2, 16), 512, 0, stream>>>(
        poolB, W1gT, nullptr, part1B, 512, GPD, C32, 1536);
    k_red1<<<512, 256, 0, stream>>>(part1B, b1g, g1B);
    // GEMM2 (128sq, split-K=4): [512,2048]x[2048,1152] -> f32 partials
    k_gemm_bf<true, false, false, false><<<dim3(9, 4, 4), 256, 0, stream>>>(
        g1B, W2gT, nullptr, part2, 512, FEAT, GPD, 512);
    // build node matrix (fused red2 for global rows)
    k_nodes<<<9792, 256, 0, stream>>>(part2, b2g, locf, nodesB);
    // GEMM3 (256sq): relu(nodes x Wp + bp) -> bf16 h [17408,1024]
    k_gemm256<false, true, true, true><<<dim3(4, 68), 512, 0, stream>>>(
        nodesB, WpT, bp, hB, NT, HID, FEAT, 0);
    // GEMM4 (256sq): z = h x Wg -> f32 [17408,512]
    k_gemm256<false, false, false, false><<<dim3(2, 68), 512, 0, stream>>>(
        hB, WgT, nullptr, z, NT, HA, HID, 0);
    // fused graph attention (512 threads)
    k_gat<<<BB, 512, 0, stream>>>(es, ed, z, a_src, a_dst, gnnB);
    // GEMM5 (256sq): out = gnn x Wllm + bllm -> f32 [17408,4096]
    k_gemm256<false, true, false, false><<<dim3(16, 68), 512, 0, stream>>>(
        gnnB, WllmT, bllm, out, NT, LLM, HA, 0);
}

// Round 9
// 541.326 us; speedup vs baseline: 1.1930x; 1.0241x over previous
//
#include <hip/hip_runtime.h>
#include <hip/hip_bf16.h>
#include <math.h>

#define BB    512
#define NPG   34
#define NT    17408
#define FEAT  1152
#define GPD   2048
#define HID   1024
#define NH    8
#define AD    64
#define HA    512
#define LLM   4096
#define EPG   272
#define NE    139264
#define C32   24576
#define CC    768

#define AS3 __attribute__((address_space(3)))
#define AS1 __attribute__((address_space(1)))

typedef __attribute__((ext_vector_type(8))) short short8v;
typedef __attribute__((ext_vector_type(4))) float f32x4;

__device__ __forceinline__ ushort f2bf(float f) {
    __hip_bfloat16 h = __float2bfloat16(f);
    return __builtin_bit_cast(ushort, h);
}
__device__ __forceinline__ float bf2f(ushort u) {
    unsigned int x = ((unsigned int)u) << 16;
    return __builtin_bit_cast(float, x);
}

// ---------------- 64x64 transpose body: W[R][Cn] -> bf16 WT[Cn][R], 16B writes ----------------
__device__ __forceinline__ void d_transpose64(const float* __restrict__ W, ushort* __restrict__ WT,
                                              int R, int Cn, int bx, int by,
                                              float (*tile)[65], int tid) {
    int c0 = bx * 64, r0 = by * 64;
    int rc = tid >> 6, cc = tid & 63;
#pragma unroll
    for (int i = 0; i < 16; i++) {
        int r = i * 4 + rc;
        tile[r][cc] = W[(size_t)(r0 + r) * Cn + c0 + cc];
    }
    __syncthreads();
#pragma unroll
    for (int i = 0; i < 2; i++) {
        int p = tid + i * 256;
        int c = p >> 3, ro = (p & 7) << 3;
        ushort u[8];
#pragma unroll
        for (int k = 0; k < 8; k++) u[k] = f2bf(tile[ro + k][c]);
        *(uint4*)&WT[(size_t)(c0 + c) * R + r0 + ro] = *(uint4*)u;
    }
}

// ---------------- pool body: [B,768,8,8,4] -> bf16 [B,24576] (2x2x2 mean) ----------------
__device__ __forceinline__ void d_pool(const float* __restrict__ gf, ushort* __restrict__ outB,
                                       int blk, int tid) {
    int t = blk * 256 + tid;
    int q = t & 15; int bc = t >> 4;
    int dO = q >> 2, hO = q & 3;
    const float* p = gf + (size_t)bc * 256 + dO * 64 + hO * 8;
    float4 r00 = *(const float4*)(p);
    float4 r01 = *(const float4*)(p + 4);
    float4 r10 = *(const float4*)(p + 32);
    float4 r11 = *(const float4*)(p + 36);
    float o0 = (r00.x + r00.y + r01.x + r01.y + r10.x + r10.y + r11.x + r11.y) * 0.125f;
    float o1 = (r00.z + r00.w + r01.z + r01.w + r10.z + r10.w + r11.z + r11.w) * 0.125f;
    int b = bc / CC, c = bc % CC;
    ushort2 v; v.x = f2bf(o0); v.y = f2bf(o1);
    *(ushort2*)(outB + (size_t)b * C32 + c * 32 + dO * 8 + hO * 2) = v;
}

// ---------------- fused prep: 5 weight transposes (64x64) + pool, one launch ----------------
__global__ __launch_bounds__(256) void k_prep(
    const float* __restrict__ W1g, ushort* __restrict__ W1gT,
    const float* __restrict__ W2g, ushort* __restrict__ W2gT,
    const float* __restrict__ Wp,  ushort* __restrict__ WpT,
    const float* __restrict__ Wg,  ushort* __restrict__ WgT,
    const float* __restrict__ Wllm, ushort* __restrict__ WllmT,
    const float* __restrict__ gf,  ushort* __restrict__ poolB) {
    __shared__ float tile[64][65];
    int blk = blockIdx.x, tid = threadIdx.x;
    if (blk < 12288) {
        d_transpose64(W1g, W1gT, C32, GPD, blk & 31, blk >> 5, tile, tid);
    } else if (blk < 12864) {
        int l = blk - 12288; d_transpose64(W2g, W2gT, GPD, FEAT, l % 18, l / 18, tile, tid);
    } else if (blk < 13152) {
        int l = blk - 12864; d_transpose64(Wp, WpT, FEAT, HID, l & 15, l >> 4, tile, tid);
    } else if (blk < 13280) {
        int l = blk - 13152; d_transpose64(Wg, WgT, HID, HA, l & 7, l >> 3, tile, tid);
    } else if (blk < 13792) {
        int l = blk - 13280; d_transpose64(Wllm, WllmT, HA, LLM, l & 63, l >> 6, tile, tid);
    } else {
        d_pool(gf, poolB, blk - 13792, tid);
    }
}

// ================= 256x256 8-phase bf16 MFMA GEMM (T2+T3+T4+T5) =================
// K-loop schedule identical to the round-4 verified template.
// SWZ: flat (y,x) XCD swizzle — only valid when gridDim.z==1 (hw lin id == computed id).
// For split-K grids the IDENTITY mapping co-locates B-panel sharers (hw_xcd = x).
#define GLDS(gp, lp) __builtin_amdgcn_global_load_lds((const AS1 void*)(gp), (AS3 void*)(lp), 16, 0, 0)
#define STAGE_A(buf, h, tt) { \
    const ushort* s_ = gAs + (size_t)(tt) * 64 + (size_t)(2 * (h)) * rK; \
    ushort* d_ = lds + (buf) * 32768 + (2 * (h)) * 4096 + (w << 9); \
    GLDS(s_, d_); GLDS(s_ + rK, d_ + 4096); }
#define STAGE_B(buf, h, tt) { \
    const ushort* s_ = gBs + (size_t)(tt) * 64 + (size_t)(2 * (h)) * rK; \
    ushort* d_ = lds + (buf) * 32768 + 16384 + (2 * (h)) * 4096 + (w << 9); \
    GLDS(s_, d_); GLDS(s_ + rK, d_ + 4096); }
#define DSRA(BO, mh) { _Pragma("unroll") for (int mf = 0; mf < 4; mf++) { \
    const ushort* p_ = lds + (BO) + aBase + ((mh) * 64 + mf * 16) * 64; \
    aF[mf][0] = *(const short8v*)(p_ + k0s); \
    aF[mf][1] = *(const short8v*)(p_ + k1s); } }
#define DSRB(BO, nh, BF) { _Pragma("unroll") for (int nf = 0; nf < 2; nf++) { \
    const ushort* p_ = lds + (BO) + bBase + ((nh) * 32 + nf * 16) * 64; \
    BF[nf][0] = *(const short8v*)(p_ + k0s); \
    BF[nf][1] = *(const short8v*)(p_ + k1s); } }
#define MM(mh, nh, BF) { \
    asm volatile("s_waitcnt lgkmcnt(0)" ::: "memory"); \
    __builtin_amdgcn_sched_barrier(0); \
    __builtin_amdgcn_s_setprio(1); \
    _Pragma("unroll") for (int mf = 0; mf < 4; mf++) \
    _Pragma("unroll") for (int nf = 0; nf < 2; nf++) { \
        acc[(mh)*4+mf][(nh)*2+nf] = __builtin_amdgcn_mfma_f32_16x16x32_bf16(aF[mf][0], BF[nf][0], acc[(mh)*4+mf][(nh)*2+nf], 0, 0, 0); \
        acc[(mh)*4+mf][(nh)*2+nf] = __builtin_amdgcn_mfma_f32_16x16x32_bf16(aF[mf][1], BF[nf][1], acc[(mh)*4+mf][(nh)*2+nf], 0, 0, 0); } \
    __builtin_amdgcn_s_setprio(0); }
#define BAR __builtin_amdgcn_s_barrier()
#define VMW4 { asm volatile("s_waitcnt vmcnt(4)" ::: "memory"); __builtin_amdgcn_sched_barrier(0); }

template<bool SWZ, bool SPLITK, bool BIAS, bool RELU, bool OUTBF>
__global__ __launch_bounds__(512, 2) void k_gemm256(
    const ushort* __restrict__ A, const ushort* __restrict__ BT,
    const float* __restrict__ bias, void* __restrict__ Cout,
    int M, int N, int K, int kChunk) {
    __shared__ ushort lds[65536];            // 128 KiB: [buf][A 32KB | B 32KB]
    const int t = threadIdx.x;
    const int w = t >> 6, l = t & 63;
    const int wm = w >> 2, wn = w & 3;
    int m0, n0;
    if (SWZ) {
        const int gx = gridDim.x;
        const int nwg = gx * gridDim.y;
        const int id = blockIdx.y * gx + blockIdx.x;
        const int qx = nwg >> 3, rx = nwg & 7;
        const int xcd = id & 7, pos = id >> 3;
        const int nid = (xcd < rx ? xcd * (qx + 1) : rx * (qx + 1) + (xcd - rx) * qx) + pos;
        m0 = (nid / gx) * 256; n0 = (nid % gx) * 256;
    } else {
        m0 = blockIdx.y * 256; n0 = blockIdx.x * 256;
    }
    const int kBase = SPLITK ? blockIdx.z * kChunk : 0;
    const int NTt = (SPLITK ? kChunk : K) / 64;

    // staging source: linear LDS dest; inverse swizzle folded into global k-offset
    const int rowLo = t >> 3;
    const int keSrc = ((t & 7) << 3) ^ (((rowLo >> 2) & 1) << 5) ^ (((rowLo >> 3) & 1) << 4);
    const ushort* gAs = A + (size_t)(m0 + rowLo) * K + kBase + keSrc;
    const ushort* gBs = BT + (size_t)(n0 + rowLo) * K + kBase + keSrc;
    const size_t rK = (size_t)64 * K;

    // fragment read geometry (swizzled ds_read addresses)
    const int fcol = l & 15, fk = (l >> 4) << 3;
    const int flipR = (((l >> 2) & 1) << 5) | (((l >> 3) & 1) << 4);
    const int k0s = fk ^ flipR;
    const int k1s = fk ^ 32 ^ flipR;
    const int aBase = (wm * 128 + fcol) * 64;
    const int bBase = 16384 + (wn * 64 + fcol) * 64;

    short8v aF[4][2], bF0[2][2], bF1[2][2];
    f32x4 acc[8][4] = {};

    // prologue: tile0 {B0,B1,A0,A1} + tile1 {B0,B1}; confirm tile0
    STAGE_B(0, 0, 0); STAGE_B(0, 1, 0); STAGE_A(0, 0, 0); STAGE_A(0, 1, 0);
    STAGE_B(1, 0, 1); STAGE_B(1, 1, 1);
    VMW4;
    BAR;

    const int NITER = NTt >> 1;
    for (int it = 0; it < NITER; ++it) {
        const int t1 = 2 * it + 1;
        const int t2r = 2 * it + 2, t3r = 2 * it + 3;
        const int t2 = t2r < NTt ? t2r : 0;   // clamped dummies keep vmcnt uniform
        const int t3 = t3r < NTt ? t3r : 0;
        DSRA(0, 0); DSRB(0, 0, bF0); STAGE_A(1, 0, t1);
        BAR; MM(0, 0, bF0); BAR;
        DSRB(0, 1, bF1); STAGE_A(1, 1, t1);
        BAR; MM(0, 1, bF1); BAR;
        DSRA(0, 1); STAGE_B(0, 0, t2);
        BAR; MM(1, 1, bF1); BAR;
        STAGE_B(0, 1, t2); VMW4;
        BAR; MM(1, 0, bF0); BAR;
        DSRA(32768, 0); DSRB(32768, 0, bF0); STAGE_A(0, 0, t2);
        BAR; MM(0, 0, bF0); BAR;
        DSRB(32768, 1, bF1); STAGE_A(0, 1, t2);
        BAR; MM(0, 1, bF1); BAR;
        DSRA(32768, 1); STAGE_B(1, 0, t3);
        BAR; MM(1, 1, bF1); BAR;
        STAGE_B(1, 1, t3); VMW4;
        BAR; MM(1, 0, bF0); BAR;
    }
    asm volatile("s_waitcnt vmcnt(0)" ::: "memory");
    BAR;   // all waves drained their in-flight LDS writes before LDS reuse

    // ---- LDS-staged vectorized epilogue: 4 passes of 32 rows x 64 cols f32 ----
    const int orow = (l >> 4) << 2;
    float* eph = ((float*)lds) + w * 2176;   // wave-private 32x68 f32 (8.5 KB)
    const int ecol = (l & 15) << 2;
    const int erow4 = l >> 4;
#pragma unroll
    for (int pass = 0; pass < 4; pass++) {
#pragma unroll
        for (int mi = 0; mi < 2; mi++) {
            int mf = pass * 2 + mi;
#pragma unroll
            for (int nf = 0; nf < 4; nf++)
#pragma unroll
                for (int r = 0; r < 4; r++)
                    eph[(mi * 16 + orow + r) * 68 + nf * 16 + fcol] = acc[mf][nf][r];
        }
#pragma unroll
        for (int g = 0; g < 8; g++) {
            int lrow = g * 4 + erow4;
            f32x4 v = *(f32x4*)&eph[lrow * 68 + ecol];
            int row = m0 + wm * 128 + pass * 32 + lrow;
            int col = n0 + wn * 64 + ecol;
            if (BIAS) {
                float4 bb = *(const float4*)(bias + col);
                v[0] += bb.x; v[1] += bb.y; v[2] += bb.z; v[3] += bb.w;
            }
            if (RELU) {
#pragma unroll
                for (int q = 0; q < 4; q++) v[q] = v[q] > 0.f ? v[q] : 0.f;
            }
            size_t off = (size_t)row * N + col;
            if (SPLITK) off += (size_t)blockIdx.z * (size_t)M * N;
            if (OUTBF) {
                ushort4 u;
                u.x = f2bf(v[0]); u.y = f2bf(v[1]); u.z = f2bf(v[2]); u.w = f2bf(v[3]);
                *(ushort4*)&((ushort*)Cout)[off] = u;
            } else {
                float4 fv = {v[0], v[1], v[2], v[3]};
                *(float4*)&((float*)Cout)[off] = fv;
            }
        }
    }
}

// ---------------- 128x128 m97-style bf16 GEMM (kept for GEMM2, N=1152) ----------------
template<bool SPLITK, bool BIAS, bool RELU, bool OUTBF>
__global__ __launch_bounds__(256) void k_gemm_bf(
    const ushort* __restrict__ A, const ushort* __restrict__ BT,
    const float* __restrict__ bias, void* __restrict__ Cout,
    int M, int N, int K, int kChunk) {
    __shared__ ushort lA[128 * 32];
    __shared__ ushort lB[128 * 32];
    const int t = threadIdx.x;
    const int w = t >> 6, l = t & 63;
    const int m0 = blockIdx.y * 128, n0 = blockIdx.x * 128;
    const int kLen = SPLITK ? kChunk : K;
    const int k0 = SPLITK ? blockIdx.z * kChunk : 0;
    const int srow = w * 16 + (l >> 2);
    const int skq = (l & 3) << 3;
    const ushort* gA = A + (size_t)(m0 + srow) * K + k0 + skq;
    const ushort* gB = BT + (size_t)(n0 + srow) * K + k0 + skq;
    ushort* lA0 = lA + w * 512;
    ushort* lB0 = lB + w * 512;
    const size_t str64 = (size_t)64 * K;
    const int wr = (w >> 1) << 6, wc = (w & 1) << 6;
    const int fcol = l & 15, fk = (l >> 4) << 3;

    f32x4 acc[4][4] = {};
    for (int kk = 0; kk < kLen; kk += 32) {
        __syncthreads();
        GLDS(gA + kk,         lA0);
        GLDS(gA + kk + str64, lA0 + 2048);
        GLDS(gB + kk,         lB0);
        GLDS(gB + kk + str64, lB0 + 2048);
        __syncthreads();
        short8v a[4], b[4];
#pragma unroll
        for (int f = 0; f < 4; f++) {
            a[f] = *(const short8v*)(lA + (wr + f * 16 + fcol) * 32 + fk);
            b[f] = *(const short8v*)(lB + (wc + f * 16 + fcol) * 32 + fk);
        }
#pragma unroll
        for (int i = 0; i < 4; i++)
#pragma unroll
            for (int j = 0; j < 4; j++)
                acc[i][j] = __builtin_amdgcn_mfma_f32_16x16x32_bf16(a[i], b[j], acc[i][j], 0, 0, 0);
    }
    const int orow = (l >> 4) << 2;
#pragma unroll
    for (int i = 0; i < 4; i++) {
#pragma unroll
        for (int j = 0; j < 4; j++) {
            int col = n0 + wc + j * 16 + fcol;
            float bv = BIAS ? bias[col] : 0.f;
#pragma unroll
            for (int r = 0; r < 4; r++) {
                int row = m0 + wr + i * 16 + orow + r;
                float v = acc[i][j][r] + bv;
                if (RELU) v = v > 0.f ? v : 0.f;
                if (OUTBF) {
                    ((ushort*)Cout)[(size_t)row * N + col] = f2bf(v);
                } else {
                    size_t off = (size_t)row * N + col;
                    if (SPLITK) off += (size_t)blockIdx.z * (size_t)M * N;
                    ((float*)Cout)[off] = v;
                }
            }
        }
    }
}

// ---------------- reduce GEMM1 bf16 partials + b1g + relu -> bf16 g1 (8 elems/thread) ----------------
__global__ __launch_bounds__(256) void k_red1(const ushort* __restrict__ part,
                                              const float* __restrict__ b1g,
                                              ushort* __restrict__ g1B) {
    int i8 = (blockIdx.x * 256 + threadIdx.x) * 8;   // over 512*2048
    float v[8];
#pragma unroll
    for (int k = 0; k < 8; k++) v[k] = b1g[(i8 + k) & (GPD - 1)];
#pragma unroll
    for (int q = 0; q < 16; q++) {
        uint4 pk = *(const uint4*)(part + (size_t)q * 1048576 + i8);
        const ushort* pu = (const ushort*)&pk;
#pragma unroll
        for (int k = 0; k < 8; k++) v[k] += bf2f(pu[k]);
    }
    ushort u[8];
#pragma unroll
    for (int k = 0; k < 8; k++) u[k] = f2bf(v[k] > 0.f ? v[k] : 0.f);
    *(uint4*)&g1B[i8] = *(uint4*)u;
}

// ---------------- build bf16 node matrix [NT][FEAT]; fused red2 for global rows ----------------
__global__ __launch_bounds__(256) void k_nodes(const float* __restrict__ part2,
                                               const float* __restrict__ b2g,
                                               const float* __restrict__ locf,
                                               ushort* __restrict__ nodesB) {
    int idx = blockIdx.x * 256 + threadIdx.x;   // over NT*144 = 2,506,752 16B-chunks
    int node = idx / 144, cc = idx - node * 144;
    int b = node / NPG, j = node - b * NPG;
    int c = cc * 8;
    ushort* dst = nodesB + (size_t)node * FEAT + c;
    if (j == 0) {
        // fused red2: bias + 4 split-K partials (ascending, same order as k_red)
        float v[8];
        float4 b0 = *(const float4*)(b2g + c), b1 = *(const float4*)(b2g + c + 4);
        v[0] = b0.x; v[1] = b0.y; v[2] = b0.z; v[3] = b0.w;
        v[4] = b1.x; v[5] = b1.y; v[6] = b1.z; v[7] = b1.w;
#pragma unroll
        for (int q = 0; q < 4; q++) {
            const float* pp = part2 + (size_t)q * 589824 + (size_t)b * FEAT + c;
            float4 p0 = *(const float4*)pp, p1 = *(const float4*)(pp + 4);
            v[0] += p0.x; v[1] += p0.y; v[2] += p0.z; v[3] += p0.w;
            v[4] += p1.x; v[5] += p1.y; v[6] += p1.z; v[7] += p1.w;
        }
        ushort u[8];
#pragma unroll
        for (int k = 0; k < 8; k++) u[k] = f2bf(v[k]);
        *(uint4*)dst = *(uint4*)u;
    } else {
        const float* s = locf + ((size_t)b * 33 + (j - 1)) * FEAT + c;
        float4 v0 = *(const float4*)s, v1 = *(const float4*)(s + 4);
        ushort u[8] = {f2bf(v0.x), f2bf(v0.y), f2bf(v0.z), f2bf(v0.w),
                       f2bf(v1.x), f2bf(v1.y), f2bf(v1.z), f2bf(v1.w)};
        *(uint4*)dst = *(uint4*)u;
    }
}

// ---------------- fused GAT: scores + per-graph softmax + aggregation ----------------
// one block per graph, 512 threads; math identical to the round-8 verified version.
// Scatter replaced by parallel rank (same ascending-e bucket order -> bit-identical).
__global__ __launch_bounds__(512) void k_gat(const int* __restrict__ es, const int* __restrict__ ed,
                                             const float* __restrict__ z,
                                             const float* __restrict__ a_src,
                                             const float* __restrict__ a_dst,
                                             ushort* __restrict__ gnnB) {
    __shared__ float zt[NPG][520];                   // padded rows (70.7 KB)
    __shared__ float sps[NPG][NH], spd[NPG][NH], sm[NPG][NH], sden[NPG][NH];
    __shared__ float esc[EPG][NH];
    __shared__ int srcl[EPG], dll[EPG], order[EPG], cnt[NPG], bstart[NPG + 1];
    int b = blockIdx.x, t = threadIdx.x;
    for (int i = t; i < NPG * 128; i += 512) {
        int n = i >> 7, c4 = (i & 127) << 2;
        *(float4*)&zt[n][c4] = *(const float4*)&z[((size_t)b * NPG + n) * HA + c4];
    }
    for (int e = t; e < EPG; e += 512) {
        srcl[e] = es[b * EPG + e] - b * NPG;
        dll[e]  = ed[b * EPG + e] - b * NPG;
    }
    if (t < NPG) cnt[t] = 0;
    __syncthreads();
    {
        int wv = t >> 6, l = t & 63;
        for (int n = wv; n < NPG; n += 8) {
            float s[NH], d[NH];
#pragma unroll
            for (int i = 0; i < NH; i++) {
                float zv = zt[n][i * 64 + l];
                s[i] = zv * a_src[i * 64 + l];
                d[i] = zv * a_dst[i * 64 + l];
            }
#pragma unroll
            for (int i = 0; i < NH; i++) {
#pragma unroll
                for (int off = 32; off > 0; off >>= 1) {
                    s[i] += __shfl_xor(s[i], off);
                    d[i] += __shfl_xor(d[i], off);
                }
            }
            if (l == 0) {
#pragma unroll
                for (int i = 0; i < NH; i++) { sps[n][i] = s[i]; spd[n][i] = d[i]; }
            }
        }
    }
    for (int e = t; e < EPG; e += 512) atomicAdd(&cnt[dll[e]], 1);
    __syncthreads();
    if (t == 0) {   // tiny serial prefix over 34 nodes
        int s = 0;
        for (int n = 0; n < NPG; n++) { bstart[n] = s; s += cnt[n]; }
        bstart[NPG] = s;
    }
    __syncthreads();
    // parallel rank: rank[e] = #{e' < e : dst e' == dst e}; order identical to serial scatter
    if (t < EPG) {
        int myd = dll[t];
        int rank = 0;
        for (int e2 = 0; e2 < EPG; e2++) {      // uniform index -> LDS broadcast reads
            int d2 = dll[e2];
            rank += (e2 < t && d2 == myd) ? 1 : 0;
        }
        order[bstart[myd] + rank] = t;
    }
    __syncthreads();
    for (int i = t; i < EPG * NH; i += 512) {
        int e = i >> 3, h = i & 7;
        float sc = sps[srcl[e]][h] + spd[dll[e]][h];
        esc[e][h] = sc > 0.f ? sc : 0.2f * sc;
    }
    __syncthreads();
    for (int i = t; i < NPG * NH; i += 512) {
        int n = i >> 3, h = i & 7;
        float m = -INFINITY;
        for (int j = bstart[n]; j < bstart[n + 1]; j++) m = fmaxf(m, esc[order[j]][h]);
        if (m == -INFINITY) m = 0.f;
        float den = 0.f;
        for (int j = bstart[n]; j < bstart[n + 1]; j++) den += expf(esc[order[j]][h] - m);
        sm[n][h] = m; sden[n][h] = den;
    }
    __syncthreads();
    for (int i = t; i < EPG * NH; i += 512) {
        int e = i >> 3, h = i & 7;
        esc[e][h] = expf(esc[e][h] - sm[dll[e]][h]) / (sden[dll[e]][h] + 1e-9f);
    }
    __syncthreads();
    for (int c = t; c < NPG * 64; c += 512) {
        int n = c >> 6, rem = c & 63, h = rem >> 3, d0 = (rem & 7) << 3;
        float acc[8] = {};
        for (int j = bstart[n]; j < bstart[n + 1]; j++) {
            int e = order[j];
            float a = esc[e][h];
            const float* zp = &zt[srcl[e]][h * 64 + d0];
#pragma unroll
            for (int q = 0; q < 8; q++) acc[q] = fmaf(a, zp[q], acc[q]);
        }
        ushort u[8];
#pragma unroll
        for (int q = 0; q < 8; q++) u[q] = f2bf(acc[q]);
        *(uint4*)&gnnB[((size_t)b * NPG + n) * HA + h * 64 + d0] = *(uint4*)u;
    }
}

extern "C" void kernel_launch(void* const* d_in, const int* in_sizes, int n_in,
                              void* d_out, int out_size, void* d_ws, size_t ws_size,
                              hipStream_t stream) {
    const float* locf  = (const float*)d_in[0];
    const float* gf    = (const float*)d_in[1];
    const int*   ei    = (const int*)d_in[2];
    const float* W1g   = (const float*)d_in[3];
    const float* b1g   = (const float*)d_in[4];
    const float* W2g   = (const float*)d_in[5];
    const float* b2g   = (const float*)d_in[6];
    const float* Wp    = (const float*)d_in[7];
    const float* bp    = (const float*)d_in[8];
    const float* Wg    = (const float*)d_in[9];
    const float* a_src = (const float*)d_in[10];
    const float* a_dst = (const float*)d_in[11];
    const float* Wllm  = (const float*)d_in[12];
    const float* bllm  = (const float*)d_in[13];
    float* out = (float*)d_out;
    float* ws  = (float*)d_ws;
    const int* es = ei;
    const int* ed = ei + NE;

    // d_out scratch layout (float offsets; every region dead before GEMM5 overwrite)
    float*  z      = out;                               // [0, 8,912,896)
    ushort* W1gT   = (ushort*)(out + 8912896);          // dead after GEMM1
    ushort* hB     = (ushort*)(out + 8912896);          // overlaps W1gT, written GEMM3
    ushort* poolB  = (ushort*)(out + 34078720);
    ushort* part1B = (ushort*)(out + 40370176);         // 16 x 512x2048 bf16 — dead after red1
    ushort* nodesB = (ushort*)(out + 40370176);         // overlaps dead part1B
    ushort* g1B    = (ushort*)(out + 57147392);
    ushort* W2gT   = (ushort*)(out + 57671680);
    ushort* WpT    = (ushort*)(out + 58851328);
    ushort* WgT    = (ushort*)(out + 59441152);
    float*  part2  = out + 59998208;                    // 4 x 512x1152 f32 (ends 62.4M < 71.3M)
    // d_ws layout (GEMM5 inputs live here, never in d_out)
    ushort* WllmT = (ushort*)ws;
    ushort* gnnB  = (ushort*)(ws + 1048576);

    // fused transposes (64x64, 16B writes) + pool
    k_prep<<<38368, 256, 0, stream>>>(W1g, W1gT, W2g, W2gT, Wp, WpT, Wg, WgT,
                                      Wllm, WllmT, gf, poolB);
    // GEMM1 (256sq 8-phase, split-K=16, IDENTITY mapping: hw_xcd = x co-locates B-panels)
    k_gemm256<false, true, false, false, true><<<dim3(8, 2, 16), 512, 0, stream>>>(
        poolB, W1gT, nullptr, part1B, 512, GPD, C32, 1536);
    k_red1<<<512, 256, 0, stream>>>(part1B, b1g, g1B);
    // GEMM2 (128sq, split-K=4): [512,2048]x[2048,1152] -> f32 partials
    k_gemm_bf<true, false, false, false><<<dim3(9, 4, 4), 256, 0, stream>>>(
        g1B, W2gT, nullptr, part2, 512, FEAT, GPD, 512);
    // build node matrix (fused red2 for global rows)
    k_nodes<<<9792, 256, 0, stream>>>(part2, b2g, locf, nodesB);
    // GEMM3 (256sq, swizzled): relu(nodes x Wp + bp) -> bf16 h [17408,1024]
    k_gemm256<true, false, true, true, true><<<dim3(4, 68), 512, 0, stream>>>(
        nodesB, WpT, bp, hB, NT, HID, FEAT, 0);
    // GEMM4 (256sq, swizzled): z = h x Wg -> f32 [17408,512]
    k_gemm256<true, false, false, false, false><<<dim3(2, 68), 512, 0, stream>>>(
        hB, WgT, nullptr, z, NT, HA, HID, 0);
    // fused graph attention (512 threads, parallel rank)
    k_gat<<<BB, 512, 0, stream>>>(es, ed, z, a_src, a_dst, gnnB);
    // GEMM5 (256sq, swizzled): out = gnn x Wllm + bllm -> f32 [17408,4096]
    k_gemm256<true, false, true, false, false><<<dim3(16, 68), 512, 0, stream>>>(
        gnnB, WllmT, bllm, out, NT, LLM, HA, 0);
}

// Round 10
// 526.996 us; speedup vs baseline: 1.2254x; 1.0272x over previous
//
#include <hip/hip_runtime.h>
#include <hip/hip_bf16.h>
#include <math.h>

#define BB    512
#define NPG   34
#define NT    17408
#define FEAT  1152
#define GPD   2048
#define HID   1024
#define NH    8
#define AD    64
#define HA    512
#define LLM   4096
#define EPG   272
#define NE    139264
#define C32   24576
#define CC    768

#define AS3 __attribute__((address_space(3)))
#define AS1 __attribute__((address_space(1)))

typedef __attribute__((ext_vector_type(8))) short short8v;
typedef __attribute__((ext_vector_type(4))) float f32x4;
typedef __attribute__((ext_vector_type(4))) ushort u16x4;

__device__ __forceinline__ ushort f2bf(float f) {
    __hip_bfloat16 h = __float2bfloat16(f);
    return __builtin_bit_cast(ushort, h);
}
__device__ __forceinline__ float bf2f(ushort u) {
    unsigned int x = ((unsigned int)u) << 16;
    return __builtin_bit_cast(float, x);
}

// ---------------- 64x64 transpose body: W[R][Cn] -> bf16 WT[Cn][R], 16B writes ----------------
__device__ __forceinline__ void d_transpose64(const float* __restrict__ W, ushort* __restrict__ WT,
                                              int R, int Cn, int bx, int by,
                                              float (*tile)[65], int tid) {
    int c0 = bx * 64, r0 = by * 64;
    int rc = tid >> 6, cc = tid & 63;
#pragma unroll
    for (int i = 0; i < 16; i++) {
        int r = i * 4 + rc;
        tile[r][cc] = W[(size_t)(r0 + r) * Cn + c0 + cc];
    }
    __syncthreads();
#pragma unroll
    for (int i = 0; i < 2; i++) {
        int p = tid + i * 256;
        int c = p >> 3, ro = (p & 7) << 3;
        ushort u[8];
#pragma unroll
        for (int k = 0; k < 8; k++) u[k] = f2bf(tile[ro + k][c]);
        *(uint4*)&WT[(size_t)(c0 + c) * R + r0 + ro] = *(uint4*)u;
    }
}

// ---------------- pool body: [B,768,8,8,4] -> bf16 [B,24576] (2x2x2 mean) ----------------
__device__ __forceinline__ void d_pool(const float* __restrict__ gf, ushort* __restrict__ outB,
                                       int blk, int tid) {
    int t = blk * 256 + tid;
    int q = t & 15; int bc = t >> 4;
    int dO = q >> 2, hO = q & 3;
    const float* p = gf + (size_t)bc * 256 + dO * 64 + hO * 8;
    float4 r00 = *(const float4*)(p);
    float4 r01 = *(const float4*)(p + 4);
    float4 r10 = *(const float4*)(p + 32);
    float4 r11 = *(const float4*)(p + 36);
    float o0 = (r00.x + r00.y + r01.x + r01.y + r10.x + r10.y + r11.x + r11.y) * 0.125f;
    float o1 = (r00.z + r00.w + r01.z + r01.w + r10.z + r10.w + r11.z + r11.w) * 0.125f;
    int b = bc / CC, c = bc % CC;
    ushort2 v; v.x = f2bf(o0); v.y = f2bf(o1);
    *(ushort2*)(outB + (size_t)b * C32 + c * 32 + dO * 8 + hO * 2) = v;
}

// ---------------- fused prep: 5 weight transposes (64x64) + pool, one launch ----------------
__global__ __launch_bounds__(256) void k_prep(
    const float* __restrict__ W1g, ushort* __restrict__ W1gT,
    const float* __restrict__ W2g, ushort* __restrict__ W2gT,
    const float* __restrict__ Wp,  ushort* __restrict__ WpT,
    const float* __restrict__ Wg,  ushort* __restrict__ WgT,
    const float* __restrict__ Wllm, ushort* __restrict__ WllmT,
    const float* __restrict__ gf,  ushort* __restrict__ poolB) {
    __shared__ float tile[64][65];
    int blk = blockIdx.x, tid = threadIdx.x;
    if (blk < 12288) {
        d_transpose64(W1g, W1gT, C32, GPD, blk & 31, blk >> 5, tile, tid);
    } else if (blk < 12864) {
        int l = blk - 12288; d_transpose64(W2g, W2gT, GPD, FEAT, l % 18, l / 18, tile, tid);
    } else if (blk < 13152) {
        int l = blk - 12864; d_transpose64(Wp, WpT, FEAT, HID, l & 15, l >> 4, tile, tid);
    } else if (blk < 13280) {
        int l = blk - 13152; d_transpose64(Wg, WgT, HID, HA, l & 7, l >> 3, tile, tid);
    } else if (blk < 13792) {
        int l = blk - 13280; d_transpose64(Wllm, WllmT, HA, LLM, l & 63, l >> 6, tile, tid);
    } else {
        d_pool(gf, poolB, blk - 13792, tid);
    }
}

// ================= 256x256 8-phase bf16 MFMA GEMM (T2+T3+T4+T5) =================
// K-loop schedule identical to the round-4 verified template.
// SWZ only when gridDim.z==1; split-K grids use identity (hw_xcd = x co-locates B-panels).
// NTST: nontemporal epilogue stores for streamed outputs.
#define GLDS(gp, lp) __builtin_amdgcn_global_load_lds((const AS1 void*)(gp), (AS3 void*)(lp), 16, 0, 0)
#define STAGE_A(buf, h, tt) { \
    const ushort* s_ = gAs + (size_t)(tt) * 64 + (size_t)(2 * (h)) * rK; \
    ushort* d_ = lds + (buf) * 32768 + (2 * (h)) * 4096 + (w << 9); \
    GLDS(s_, d_); GLDS(s_ + rK, d_ + 4096); }
#define STAGE_B(buf, h, tt) { \
    const ushort* s_ = gBs + (size_t)(tt) * 64 + (size_t)(2 * (h)) * rK; \
    ushort* d_ = lds + (buf) * 32768 + 16384 + (2 * (h)) * 4096 + (w << 9); \
    GLDS(s_, d_); GLDS(s_ + rK, d_ + 4096); }
#define DSRA(BO, mh) { _Pragma("unroll") for (int mf = 0; mf < 4; mf++) { \
    const ushort* p_ = lds + (BO) + aBase + ((mh) * 64 + mf * 16) * 64; \
    aF[mf][0] = *(const short8v*)(p_ + k0s); \
    aF[mf][1] = *(const short8v*)(p_ + k1s); } }
#define DSRB(BO, nh, BF) { _Pragma("unroll") for (int nf = 0; nf < 2; nf++) { \
    const ushort* p_ = lds + (BO) + bBase + ((nh) * 32 + nf * 16) * 64; \
    BF[nf][0] = *(const short8v*)(p_ + k0s); \
    BF[nf][1] = *(const short8v*)(p_ + k1s); } }
#define MM(mh, nh, BF) { \
    asm volatile("s_waitcnt lgkmcnt(0)" ::: "memory"); \
    __builtin_amdgcn_sched_barrier(0); \
    __builtin_amdgcn_s_setprio(1); \
    _Pragma("unroll") for (int mf = 0; mf < 4; mf++) \
    _Pragma("unroll") for (int nf = 0; nf < 2; nf++) { \
        acc[(mh)*4+mf][(nh)*2+nf] = __builtin_amdgcn_mfma_f32_16x16x32_bf16(aF[mf][0], BF[nf][0], acc[(mh)*4+mf][(nh)*2+nf], 0, 0, 0); \
        acc[(mh)*4+mf][(nh)*2+nf] = __builtin_amdgcn_mfma_f32_16x16x32_bf16(aF[mf][1], BF[nf][1], acc[(mh)*4+mf][(nh)*2+nf], 0, 0, 0); } \
    __builtin_amdgcn_s_setprio(0); }
#define BAR __builtin_amdgcn_s_barrier()
#define VMW4 { asm volatile("s_waitcnt vmcnt(4)" ::: "memory"); __builtin_amdgcn_sched_barrier(0); }

template<bool SWZ, bool SPLITK, bool BIAS, bool RELU, bool OUTBF, bool NTST>
__global__ __launch_bounds__(512, 2) void k_gemm256(
    const ushort* __restrict__ A, const ushort* __restrict__ BT,
    const float* __restrict__ bias, void* __restrict__ Cout,
    int M, int N, int K, int kChunk) {
    __shared__ ushort lds[65536];            // 128 KiB: [buf][A 32KB | B 32KB]
    const int t = threadIdx.x;
    const int w = t >> 6, l = t & 63;
    const int wm = w >> 2, wn = w & 3;
    int m0, n0;
    if (SWZ) {
        const int gx = gridDim.x;
        const int nwg = gx * gridDim.y;
        const int id = blockIdx.y * gx + blockIdx.x;
        const int qx = nwg >> 3, rx = nwg & 7;
        const int xcd = id & 7, pos = id >> 3;
        const int nid = (xcd < rx ? xcd * (qx + 1) : rx * (qx + 1) + (xcd - rx) * qx) + pos;
        m0 = (nid / gx) * 256; n0 = (nid % gx) * 256;
    } else {
        m0 = blockIdx.y * 256; n0 = blockIdx.x * 256;
    }
    const int kBase = SPLITK ? blockIdx.z * kChunk : 0;
    const int NTt = (SPLITK ? kChunk : K) / 64;

    // staging source: linear LDS dest; inverse swizzle folded into global k-offset
    const int rowLo = t >> 3;
    const int keSrc = ((t & 7) << 3) ^ (((rowLo >> 2) & 1) << 5) ^ (((rowLo >> 3) & 1) << 4);
    const ushort* gAs = A + (size_t)(m0 + rowLo) * K + kBase + keSrc;
    const ushort* gBs = BT + (size_t)(n0 + rowLo) * K + kBase + keSrc;
    const size_t rK = (size_t)64 * K;

    // fragment read geometry (swizzled ds_read addresses)
    const int fcol = l & 15, fk = (l >> 4) << 3;
    const int flipR = (((l >> 2) & 1) << 5) | (((l >> 3) & 1) << 4);
    const int k0s = fk ^ flipR;
    const int k1s = fk ^ 32 ^ flipR;
    const int aBase = (wm * 128 + fcol) * 64;
    const int bBase = 16384 + (wn * 64 + fcol) * 64;

    short8v aF[4][2], bF0[2][2], bF1[2][2];
    f32x4 acc[8][4] = {};

    // prologue: tile0 {B0,B1,A0,A1} + tile1 {B0,B1}; confirm tile0
    STAGE_B(0, 0, 0); STAGE_B(0, 1, 0); STAGE_A(0, 0, 0); STAGE_A(0, 1, 0);
    STAGE_B(1, 0, 1); STAGE_B(1, 1, 1);
    VMW4;
    BAR;

    const int NITER = NTt >> 1;
    for (int it = 0; it < NITER; ++it) {
        const int t1 = 2 * it + 1;
        const int t2r = 2 * it + 2, t3r = 2 * it + 3;
        const int t2 = t2r < NTt ? t2r : 0;   // clamped dummies keep vmcnt uniform
        const int t3 = t3r < NTt ? t3r : 0;
        DSRA(0, 0); DSRB(0, 0, bF0); STAGE_A(1, 0, t1);
        BAR; MM(0, 0, bF0); BAR;
        DSRB(0, 1, bF1); STAGE_A(1, 1, t1);
        BAR; MM(0, 1, bF1); BAR;
        DSRA(0, 1); STAGE_B(0, 0, t2);
        BAR; MM(1, 1, bF1); BAR;
        STAGE_B(0, 1, t2); VMW4;
        BAR; MM(1, 0, bF0); BAR;
        DSRA(32768, 0); DSRB(32768, 0, bF0); STAGE_A(0, 0, t2);
        BAR; MM(0, 0, bF0); BAR;
        DSRB(32768, 1, bF1); STAGE_A(0, 1, t2);
        BAR; MM(0, 1, bF1); BAR;
        DSRA(32768, 1); STAGE_B(1, 0, t3);
        BAR; MM(1, 1, bF1); BAR;
        STAGE_B(1, 1, t3); VMW4;
        BAR; MM(1, 0, bF0); BAR;
    }
    asm volatile("s_waitcnt vmcnt(0)" ::: "memory");
    BAR;   // all waves drained their in-flight LDS writes before LDS reuse

    // ---- LDS-staged vectorized epilogue: 4 passes of 32 rows x 64 cols f32 ----
    const int orow = (l >> 4) << 2;
    float* eph = ((float*)lds) + w * 2176;   // wave-private 32x68 f32 (8.5 KB)
    const int ecol = (l & 15) << 2;
    const int erow4 = l >> 4;
#pragma unroll
    for (int pass = 0; pass < 4; pass++) {
#pragma unroll
        for (int mi = 0; mi < 2; mi++) {
            int mf = pass * 2 + mi;
#pragma unroll
            for (int nf = 0; nf < 4; nf++)
#pragma unroll
                for (int r = 0; r < 4; r++)
                    eph[(mi * 16 + orow + r) * 68 + nf * 16 + fcol] = acc[mf][nf][r];
        }
#pragma unroll
        for (int g = 0; g < 8; g++) {
            int lrow = g * 4 + erow4;
            f32x4 v = *(f32x4*)&eph[lrow * 68 + ecol];
            int row = m0 + wm * 128 + pass * 32 + lrow;
            int col = n0 + wn * 64 + ecol;
            if (BIAS) {
                float4 bb = *(const float4*)(bias + col);
                v[0] += bb.x; v[1] += bb.y; v[2] += bb.z; v[3] += bb.w;
            }
            if (RELU) {
#pragma unroll
                for (int q = 0; q < 4; q++) v[q] = v[q] > 0.f ? v[q] : 0.f;
            }
            size_t off = (size_t)row * N + col;
            if (SPLITK) off += (size_t)blockIdx.z * (size_t)M * N;
            if (OUTBF) {
                u16x4 u;
                u[0] = f2bf(v[0]); u[1] = f2bf(v[1]); u[2] = f2bf(v[2]); u[3] = f2bf(v[3]);
                if (NTST) __builtin_nontemporal_store(u, (u16x4*)&((ushort*)Cout)[off]);
                else      *(u16x4*)&((ushort*)Cout)[off] = u;
            } else {
                if (NTST) __builtin_nontemporal_store(v, (f32x4*)&((float*)Cout)[off]);
                else      *(f32x4*)&((float*)Cout)[off] = v;
            }
        }
    }
}

// ---------------- 128x128 m97-style bf16 GEMM (GEMM2 + GEMM4) ----------------
template<bool SPLITK, bool BIAS, bool RELU, bool OUTBF>
__global__ __launch_bounds__(256) void k_gemm_bf(
    const ushort* __restrict__ A, const ushort* __restrict__ BT,
    const float* __restrict__ bias, void* __restrict__ Cout,
    int M, int N, int K, int kChunk) {
    __shared__ ushort lA[128 * 32];
    __shared__ ushort lB[128 * 32];
    const int t = threadIdx.x;
    const int w = t >> 6, l = t & 63;
    const int m0 = blockIdx.y * 128, n0 = blockIdx.x * 128;
    const int kLen = SPLITK ? kChunk : K;
    const int k0 = SPLITK ? blockIdx.z * kChunk : 0;
    const int srow = w * 16 + (l >> 2);
    const int skq = (l & 3) << 3;
    const ushort* gA = A + (size_t)(m0 + srow) * K + k0 + skq;
    const ushort* gB = BT + (size_t)(n0 + srow) * K + k0 + skq;
    ushort* lA0 = lA + w * 512;
    ushort* lB0 = lB + w * 512;
    const size_t str64 = (size_t)64 * K;
    const int wr = (w >> 1) << 6, wc = (w & 1) << 6;
    const int fcol = l & 15, fk = (l >> 4) << 3;

    f32x4 acc[4][4] = {};
    for (int kk = 0; kk < kLen; kk += 32) {
        __syncthreads();
        GLDS(gA + kk,         lA0);
        GLDS(gA + kk + str64, lA0 + 2048);
        GLDS(gB + kk,         lB0);
        GLDS(gB + kk + str64, lB0 + 2048);
        __syncthreads();
        short8v a[4], b[4];
#pragma unroll
        for (int f = 0; f < 4; f++) {
            a[f] = *(const short8v*)(lA + (wr + f * 16 + fcol) * 32 + fk);
            b[f] = *(const short8v*)(lB + (wc + f * 16 + fcol) * 32 + fk);
        }
#pragma unroll
        for (int i = 0; i < 4; i++)
#pragma unroll
            for (int j = 0; j < 4; j++)
                acc[i][j] = __builtin_amdgcn_mfma_f32_16x16x32_bf16(a[i], b[j], acc[i][j], 0, 0, 0);
    }
    const int orow = (l >> 4) << 2;
#pragma unroll
    for (int i = 0; i < 4; i++) {
#pragma unroll
        for (int j = 0; j < 4; j++) {
            int col = n0 + wc + j * 16 + fcol;
            float bv = BIAS ? bias[col] : 0.f;
#pragma unroll
            for (int r = 0; r < 4; r++) {
                int row = m0 + wr + i * 16 + orow + r;
                float v = acc[i][j][r] + bv;
                if (RELU) v = v > 0.f ? v : 0.f;
                if (OUTBF) {
                    ((ushort*)Cout)[(size_t)row * N + col] = f2bf(v);
                } else {
                    size_t off = (size_t)row * N + col;
                    if (SPLITK) off += (size_t)blockIdx.z * (size_t)M * N;
                    ((float*)Cout)[off] = v;
                }
            }
        }
    }
}

// ---------------- reduce GEMM1 bf16 partials + b1g + relu -> bf16 g1 (8 elems/thread) ----------------
__global__ __launch_bounds__(256) void k_red1(const ushort* __restrict__ part,
                                              const float* __restrict__ b1g,
                                              ushort* __restrict__ g1B) {
    int i8 = (blockIdx.x * 256 + threadIdx.x) * 8;   // over 512*2048
    float v[8];
#pragma unroll
    for (int k = 0; k < 8; k++) v[k] = b1g[(i8 + k) & (GPD - 1)];
#pragma unroll
    for (int q = 0; q < 16; q++) {
        uint4 pk = *(const uint4*)(part + (size_t)q * 1048576 + i8);
        const ushort* pu = (const ushort*)&pk;
#pragma unroll
        for (int k = 0; k < 8; k++) v[k] += bf2f(pu[k]);
    }
    ushort u[8];
#pragma unroll
    for (int k = 0; k < 8; k++) u[k] = f2bf(v[k] > 0.f ? v[k] : 0.f);
    *(uint4*)&g1B[i8] = *(uint4*)u;
}

// ---------------- build bf16 node matrix [NT][FEAT]; fused red2 (8 partials) ----------------
__global__ __launch_bounds__(256) void k_nodes(const float* __restrict__ part2,
                                               const float* __restrict__ b2g,
                                               const float* __restrict__ locf,
                                               ushort* __restrict__ nodesB) {
    int idx = blockIdx.x * 256 + threadIdx.x;   // over NT*144 = 2,506,752 16B-chunks
    int node = idx / 144, cc = idx - node * 144;
    int b = node / NPG, j = node - b * NPG;
    int c = cc * 8;
    ushort* dst = nodesB + (size_t)node * FEAT + c;
    if (j == 0) {
        float v[8];
        float4 b0 = *(const float4*)(b2g + c), b1 = *(const float4*)(b2g + c + 4);
        v[0] = b0.x; v[1] = b0.y; v[2] = b0.z; v[3] = b0.w;
        v[4] = b1.x; v[5] = b1.y; v[6] = b1.z; v[7] = b1.w;
#pragma unroll
        for (int q = 0; q < 8; q++) {
            const float* pp = part2 + (size_t)q * 589824 + (size_t)b * FEAT + c;
            float4 p0 = *(const float4*)pp, p1 = *(const float4*)(pp + 4);
            v[0] += p0.x; v[1] += p0.y; v[2] += p0.z; v[3] += p0.w;
            v[4] += p1.x; v[5] += p1.y; v[6] += p1.z; v[7] += p1.w;
        }
        ushort u[8];
#pragma unroll
        for (int k = 0; k < 8; k++) u[k] = f2bf(v[k]);
        *(uint4*)dst = *(uint4*)u;
    } else {
        const float* s = locf + ((size_t)b * 33 + (j - 1)) * FEAT + c;
        float4 v0 = *(const float4*)s, v1 = *(const float4*)(s + 4);
        ushort u[8] = {f2bf(v0.x), f2bf(v0.y), f2bf(v0.z), f2bf(v0.w),
                       f2bf(v1.x), f2bf(v1.y), f2bf(v1.z), f2bf(v1.w)};
        *(uint4*)dst = *(uint4*)u;
    }
}

// ---------------- fused GAT: scores + per-graph softmax + aggregation ----------------
// one block per graph, 512 threads; z now bf16 (converted to f32 during staging).
__global__ __launch_bounds__(512) void k_gat(const int* __restrict__ es, const int* __restrict__ ed,
                                             const ushort* __restrict__ zB,
                                             const float* __restrict__ a_src,
                                             const float* __restrict__ a_dst,
                                             ushort* __restrict__ gnnB) {
    __shared__ float zt[NPG][520];                   // padded rows (70.7 KB)
    __shared__ float sps[NPG][NH], spd[NPG][NH], sm[NPG][NH], sden[NPG][NH];
    __shared__ float esc[EPG][NH];
    __shared__ int srcl[EPG], dll[EPG], order[EPG], cnt[NPG], bstart[NPG + 1];
    int b = blockIdx.x, t = threadIdx.x;
    for (int i = t; i < NPG * 64; i += 512) {        // 8 bf16 per chunk
        int n = i >> 6, c0 = (i & 63) << 3;
        uint4 pk = *(const uint4*)&zB[((size_t)b * NPG + n) * HA + c0];
        const ushort* pu = (const ushort*)&pk;
#pragma unroll
        for (int q = 0; q < 8; q++) zt[n][c0 + q] = bf2f(pu[q]);
    }
    for (int e = t; e < EPG; e += 512) {
        srcl[e] = es[b * EPG + e] - b * NPG;
        dll[e]  = ed[b * EPG + e] - b * NPG;
    }
    if (t < NPG) cnt[t] = 0;
    __syncthreads();
    {
        int wv = t >> 6, l = t & 63;
        for (int n = wv; n < NPG; n += 8) {
            float s[NH], d[NH];
#pragma unroll
            for (int i = 0; i < NH; i++) {
                float zv = zt[n][i * 64 + l];
                s[i] = zv * a_src[i * 64 + l];
                d[i] = zv * a_dst[i * 64 + l];
            }
#pragma unroll
            for (int i = 0; i < NH; i++) {
#pragma unroll
                for (int off = 32; off > 0; off >>= 1) {
                    s[i] += __shfl_xor(s[i], off);
                    d[i] += __shfl_xor(d[i], off);
                }
            }
            if (l == 0) {
#pragma unroll
                for (int i = 0; i < NH; i++) { sps[n][i] = s[i]; spd[n][i] = d[i]; }
            }
        }
    }
    for (int e = t; e < EPG; e += 512) atomicAdd(&cnt[dll[e]], 1);
    __syncthreads();
    if (t == 0) {   // tiny serial prefix over 34 nodes
        int s = 0;
        for (int n = 0; n < NPG; n++) { bstart[n] = s; s += cnt[n]; }
        bstart[NPG] = s;
    }
    __syncthreads();
    // parallel rank: identical ascending-e bucket order to serial scatter
    if (t < EPG) {
        int myd = dll[t];
        int rank = 0;
        for (int e2 = 0; e2 < EPG; e2++) {
            int d2 = dll[e2];
            rank += (e2 < t && d2 == myd) ? 1 : 0;
        }
        order[bstart[myd] + rank] = t;
    }
    __syncthreads();
    for (int i = t; i < EPG * NH; i += 512) {
        int e = i >> 3, h = i & 7;
        float sc = sps[srcl[e]][h] + spd[dll[e]][h];
        esc[e][h] = sc > 0.f ? sc : 0.2f * sc;
    }
    __syncthreads();
    for (int i = t; i < NPG * NH; i += 512) {
        int n = i >> 3, h = i & 7;
        float m = -INFINITY;
        for (int j = bstart[n]; j < bstart[n + 1]; j++) m = fmaxf(m, esc[order[j]][h]);
        if (m == -INFINITY) m = 0.f;
        float den = 0.f;
        for (int j = bstart[n]; j < bstart[n + 1]; j++) den += expf(esc[order[j]][h] - m);
        sm[n][h] = m; sden[n][h] = den;
    }
    __syncthreads();
    for (int i = t; i < EPG * NH; i += 512) {
        int e = i >> 3, h = i & 7;
        esc[e][h] = expf(esc[e][h] - sm[dll[e]][h]) / (sden[dll[e]][h] + 1e-9f);
    }
    __syncthreads();
    for (int c = t; c < NPG * 64; c += 512) {
        int n = c >> 6, rem = c & 63, h = rem >> 3, d0 = (rem & 7) << 3;
        float acc[8] = {};
        for (int j = bstart[n]; j < bstart[n + 1]; j++) {
            int e = order[j];
            float a = esc[e][h];
            const float* zp = &zt[srcl[e]][h * 64 + d0];
#pragma unroll
            for (int q = 0; q < 8; q++) acc[q] = fmaf(a, zp[q], acc[q]);
        }
        ushort u[8];
#pragma unroll
        for (int q = 0; q < 8; q++) u[q] = f2bf(acc[q]);
        *(uint4*)&gnnB[((size_t)b * NPG + n) * HA + h * 64 + d0] = *(uint4*)u;
    }
}

extern "C" void kernel_launch(void* const* d_in, const int* in_sizes, int n_in,
                              void* d_out, int out_size, void* d_ws, size_t ws_size,
                              hipStream_t stream) {
    const float* locf  = (const float*)d_in[0];
    const float* gf    = (const float*)d_in[1];
    const int*   ei    = (const int*)d_in[2];
    const float* W1g   = (const float*)d_in[3];
    const float* b1g   = (const float*)d_in[4];
    const float* W2g   = (const float*)d_in[5];
    const float* b2g   = (const float*)d_in[6];
    const float* Wp    = (const float*)d_in[7];
    const float* bp    = (const float*)d_in[8];
    const float* Wg    = (const float*)d_in[9];
    const float* a_src = (const float*)d_in[10];
    const float* a_dst = (const float*)d_in[11];
    const float* Wllm  = (const float*)d_in[12];
    const float* bllm  = (const float*)d_in[13];
    float* out = (float*)d_out;
    float* ws  = (float*)d_ws;
    const int* es = ei;
    const int* ed = ei + NE;

    // d_out scratch layout (float offsets; every region dead before GEMM5 overwrite)
    ushort* zB     = (ushort*)out;                      // [0, 4.46M f) bf16 z
    ushort* W1gT   = (ushort*)(out + 8912896);          // dead after GEMM1
    ushort* hB     = (ushort*)(out + 8912896);          // overlaps W1gT, written GEMM3
    ushort* poolB  = (ushort*)(out + 34078720);
    ushort* part1B = (ushort*)(out + 40370176);         // 16 x 512x2048 bf16 — dead after red1
    ushort* nodesB = (ushort*)(out + 40370176);         // overlaps dead part1B
    ushort* g1B    = (ushort*)(out + 57147392);
    ushort* W2gT   = (ushort*)(out + 57671680);
    ushort* WpT    = (ushort*)(out + 58851328);
    ushort* WgT    = (ushort*)(out + 59441152);
    float*  part2  = out + 59998208;                    // 8 x 512x1152 f32 (ends 64.7M < 71.3M)
    // d_ws layout (GEMM5 inputs live here, never in d_out)
    ushort* WllmT = (ushort*)ws;
    ushort* gnnB  = (ushort*)(ws + 1048576);

    // fused transposes (64x64, 16B writes) + pool
    k_prep<<<38368, 256, 0, stream>>>(W1g, W1gT, W2g, W2gT, Wp, WpT, Wg, WgT,
                                      Wllm, WllmT, gf, poolB);
    // GEMM1 (256sq 8-phase, split-K=16, identity map, NT partial stores)
    k_gemm256<false, true, false, false, true, true><<<dim3(8, 2, 16), 512, 0, stream>>>(
        poolB, W1gT, nullptr, part1B, 512, GPD, C32, 1536);
    k_red1<<<512, 256, 0, stream>>>(part1B, b1g, g1B);
    // GEMM2 (128sq, split-K=8): [512,2048]x[2048,1152] -> f32 partials
    k_gemm_bf<true, false, false, false><<<dim3(9, 4, 8), 256, 0, stream>>>(
        g1B, W2gT, nullptr, part2, 512, FEAT, GPD, 256);
    // build node matrix (fused red2, 8 partials)
    k_nodes<<<9792, 256, 0, stream>>>(part2, b2g, locf, nodesB);
    // GEMM3 (256sq, swizzled): relu(nodes x Wp + bp) -> bf16 h [17408,1024]
    k_gemm256<true, false, true, true, true, false><<<dim3(4, 68), 512, 0, stream>>>(
        nodesB, WpT, bp, hB, NT, HID, FEAT, 0);
    // GEMM4 (128sq, full grid): z = h x Wg -> bf16 [17408,512]
    k_gemm_bf<false, false, false, true><<<dim3(4, 136), 256, 0, stream>>>(
        hB, WgT, nullptr, zB, NT, HA, HID, 0);
    // fused graph attention (512 threads, bf16 z)
    k_gat<<<BB, 512, 0, stream>>>(es, ed, zB, a_src, a_dst, gnnB);
    // GEMM5 (256sq, swizzled, NT output stores): out = gnn x Wllm + bllm -> f32
    k_gemm256<true, false, true, false, false, true><<<dim3(16, 68), 512, 0, stream>>>(
        gnnB, WllmT, bllm, out, NT, LLM, HA, 0);
}

// Round 11
// 512.548 us; speedup vs baseline: 1.2599x; 1.0282x over previous
//
#include <hip/hip_runtime.h>
#include <hip/hip_bf16.h>
#include <math.h>

#define BB    512
#define NPG   34
#define NT    17408
#define FEAT  1152
#define GPD   2048
#define HID   1024
#define NH    8
#define AD    64
#define HA    512
#define LLM   4096
#define EPG   272
#define NE    139264
#define C32   24576
#define CC    768

#define AS3 __attribute__((address_space(3)))
#define AS1 __attribute__((address_space(1)))

typedef __attribute__((ext_vector_type(8))) short short8v;
typedef __attribute__((ext_vector_type(4))) float f32x4;
typedef __attribute__((ext_vector_type(4))) ushort u16x4;

__device__ __forceinline__ ushort f2bf(float f) {
    __hip_bfloat16 h = __float2bfloat16(f);
    return __builtin_bit_cast(ushort, h);
}
__device__ __forceinline__ float bf2f(ushort u) {
    unsigned int x = ((unsigned int)u) << 16;
    return __builtin_bit_cast(float, x);
}

// ---------------- 64x64 transpose body: W[R][Cn] -> bf16 WT[Cn][R], 16B writes ----------------
__device__ __forceinline__ void d_transpose64(const float* __restrict__ W, ushort* __restrict__ WT,
                                              int R, int Cn, int bx, int by,
                                              float (*tile)[65], int tid) {
    int c0 = bx * 64, r0 = by * 64;
    int rc = tid >> 6, cc = tid & 63;
#pragma unroll
    for (int i = 0; i < 16; i++) {
        int r = i * 4 + rc;
        tile[r][cc] = W[(size_t)(r0 + r) * Cn + c0 + cc];
    }
    __syncthreads();
#pragma unroll
    for (int i = 0; i < 2; i++) {
        int p = tid + i * 256;
        int c = p >> 3, ro = (p & 7) << 3;
        ushort u[8];
#pragma unroll
        for (int k = 0; k < 8; k++) u[k] = f2bf(tile[ro + k][c]);
        *(uint4*)&WT[(size_t)(c0 + c) * R + r0 + ro] = *(uint4*)u;
    }
}

// ---------------- pool body: [B,768,8,8,4] -> bf16 [B,24576] (2x2x2 mean) ----------------
__device__ __forceinline__ void d_pool(const float* __restrict__ gf, ushort* __restrict__ outB,
                                       int blk, int tid) {
    int t = blk * 256 + tid;
    int q = t & 15; int bc = t >> 4;
    int dO = q >> 2, hO = q & 3;
    const float* p = gf + (size_t)bc * 256 + dO * 64 + hO * 8;
    float4 r00 = *(const float4*)(p);
    float4 r01 = *(const float4*)(p + 4);
    float4 r10 = *(const float4*)(p + 32);
    float4 r11 = *(const float4*)(p + 36);
    float o0 = (r00.x + r00.y + r01.x + r01.y + r10.x + r10.y + r11.x + r11.y) * 0.125f;
    float o1 = (r00.z + r00.w + r01.z + r01.w + r10.z + r10.w + r11.z + r11.w) * 0.125f;
    int b = bc / CC, c = bc % CC;
    ushort2 v; v.x = f2bf(o0); v.y = f2bf(o1);
    *(ushort2*)(outB + (size_t)b * C32 + c * 32 + dO * 8 + hO * 2) = v;
}

// ---------------- fused prep: 5 weight transposes (64x64) + pool, one launch ----------------
__global__ __launch_bounds__(256) void k_prep(
    const float* __restrict__ W1g, ushort* __restrict__ W1gT,
    const float* __restrict__ W2g, ushort* __restrict__ W2gT,
    const float* __restrict__ Wp,  ushort* __restrict__ WpT,
    const float* __restrict__ Wg,  ushort* __restrict__ WgT,
    const float* __restrict__ Wllm, ushort* __restrict__ WllmT,
    const float* __restrict__ gf,  ushort* __restrict__ poolB) {
    __shared__ float tile[64][65];
    int blk = blockIdx.x, tid = threadIdx.x;
    if (blk < 12288) {
        d_transpose64(W1g, W1gT, C32, GPD, blk & 31, blk >> 5, tile, tid);
    } else if (blk < 12864) {
        int l = blk - 12288; d_transpose64(W2g, W2gT, GPD, FEAT, l % 18, l / 18, tile, tid);
    } else if (blk < 13152) {
        int l = blk - 12864; d_transpose64(Wp, WpT, FEAT, HID, l & 15, l >> 4, tile, tid);
    } else if (blk < 13280) {
        int l = blk - 13152; d_transpose64(Wg, WgT, HID, HA, l & 7, l >> 3, tile, tid);
    } else if (blk < 13792) {
        int l = blk - 13280; d_transpose64(Wllm, WllmT, HA, LLM, l & 63, l >> 6, tile, tid);
    } else {
        d_pool(gf, poolB, blk - 13792, tid);
    }
}

// ================= 256x256 8-phase bf16 MFMA GEMM (T2+T3+T4+T5) =================
// K-loop schedule identical to the round-4 verified template.
// SWZMODE 0: identity. 1: flat (y,x) XCD swizzle (gridDim.z==1 only).
// 2: split-K z-map — hw_xcd = bx; remap (x,y,z)=(bz&7, by, (bz&8)|bx) so each XCD
//    owns 2 z-chunks x all (x,y): A- and B-chunks both single-fetch, L2-resident.
#define GLDS(gp, lp) __builtin_amdgcn_global_load_lds((const AS1 void*)(gp), (AS3 void*)(lp), 16, 0, 0)
#define STAGE_A(buf, h, tt) { \
    const ushort* s_ = gAs + (size_t)(tt) * 64 + (size_t)(2 * (h)) * rK; \
    ushort* d_ = lds + (buf) * 32768 + (2 * (h)) * 4096 + (w << 9); \
    GLDS(s_, d_); GLDS(s_ + rK, d_ + 4096); }
#define STAGE_B(buf, h, tt) { \
    const ushort* s_ = gBs + (size_t)(tt) * 64 + (size_t)(2 * (h)) * rK; \
    ushort* d_ = lds + (buf) * 32768 + 16384 + (2 * (h)) * 4096 + (w << 9); \
    GLDS(s_, d_); GLDS(s_ + rK, d_ + 4096); }
#define DSRA(BO, mh) { _Pragma("unroll") for (int mf = 0; mf < 4; mf++) { \
    const ushort* p_ = lds + (BO) + aBase + ((mh) * 64 + mf * 16) * 64; \
    aF[mf][0] = *(const short8v*)(p_ + k0s); \
    aF[mf][1] = *(const short8v*)(p_ + k1s); } }
#define DSRB(BO, nh, BF) { _Pragma("unroll") for (int nf = 0; nf < 2; nf++) { \
    const ushort* p_ = lds + (BO) + bBase + ((nh) * 32 + nf * 16) * 64; \
    BF[nf][0] = *(const short8v*)(p_ + k0s); \
    BF[nf][1] = *(const short8v*)(p_ + k1s); } }
#define MM(mh, nh, BF) { \
    asm volatile("s_waitcnt lgkmcnt(0)" ::: "memory"); \
    __builtin_amdgcn_sched_barrier(0); \
    __builtin_amdgcn_s_setprio(1); \
    _Pragma("unroll") for (int mf = 0; mf < 4; mf++) \
    _Pragma("unroll") for (int nf = 0; nf < 2; nf++) { \
        acc[(mh)*4+mf][(nh)*2+nf] = __builtin_amdgcn_mfma_f32_16x16x32_bf16(aF[mf][0], BF[nf][0], acc[(mh)*4+mf][(nh)*2+nf], 0, 0, 0); \
        acc[(mh)*4+mf][(nh)*2+nf] = __builtin_amdgcn_mfma_f32_16x16x32_bf16(aF[mf][1], BF[nf][1], acc[(mh)*4+mf][(nh)*2+nf], 0, 0, 0); } \
    __builtin_amdgcn_s_setprio(0); }
#define BAR __builtin_amdgcn_s_barrier()
#define VMW4 { asm volatile("s_waitcnt vmcnt(4)" ::: "memory"); __builtin_amdgcn_sched_barrier(0); }

template<int SWZMODE, bool SPLITK, bool BIAS, bool RELU, bool OUTBF, bool NTST>
__global__ __launch_bounds__(512, 2) void k_gemm256(
    const ushort* __restrict__ A, const ushort* __restrict__ BT,
    const float* __restrict__ bias, void* __restrict__ Cout,
    int M, int N, int K, int kChunk) {
    __shared__ ushort lds[65536];            // 128 KiB: [buf][A 32KB | B 32KB]
    const int t = threadIdx.x;
    const int w = t >> 6, l = t & 63;
    const int wm = w >> 2, wn = w & 3;
    int m0, n0, kz;
    if (SWZMODE == 1) {
        const int gx = gridDim.x;
        const int nwg = gx * gridDim.y;
        const int id = blockIdx.y * gx + blockIdx.x;
        const int qx = nwg >> 3, rx = nwg & 7;
        const int xcd = id & 7, pos = id >> 3;
        const int nid = (xcd < rx ? xcd * (qx + 1) : rx * (qx + 1) + (xcd - rx) * qx) + pos;
        m0 = (nid / gx) * 256; n0 = (nid % gx) * 256; kz = blockIdx.z;
    } else if (SWZMODE == 2) {
        m0 = blockIdx.y * 256;
        n0 = (blockIdx.z & 7) * 256;
        kz = (blockIdx.z & 8) | blockIdx.x;
    } else {
        m0 = blockIdx.y * 256; n0 = blockIdx.x * 256; kz = blockIdx.z;
    }
    const int kBase = SPLITK ? kz * kChunk : 0;
    const int NTt = (SPLITK ? kChunk : K) / 64;

    // staging source: linear LDS dest; inverse swizzle folded into global k-offset
    const int rowLo = t >> 3;
    const int keSrc = ((t & 7) << 3) ^ (((rowLo >> 2) & 1) << 5) ^ (((rowLo >> 3) & 1) << 4);
    const ushort* gAs = A + (size_t)(m0 + rowLo) * K + kBase + keSrc;
    const ushort* gBs = BT + (size_t)(n0 + rowLo) * K + kBase + keSrc;
    const size_t rK = (size_t)64 * K;

    // fragment read geometry (swizzled ds_read addresses)
    const int fcol = l & 15, fk = (l >> 4) << 3;
    const int flipR = (((l >> 2) & 1) << 5) | (((l >> 3) & 1) << 4);
    const int k0s = fk ^ flipR;
    const int k1s = fk ^ 32 ^ flipR;
    const int aBase = (wm * 128 + fcol) * 64;
    const int bBase = 16384 + (wn * 64 + fcol) * 64;

    short8v aF[4][2], bF0[2][2], bF1[2][2];
    f32x4 acc[8][4] = {};

    // prologue: tile0 {B0,B1,A0,A1} + tile1 {B0,B1}; confirm tile0
    STAGE_B(0, 0, 0); STAGE_B(0, 1, 0); STAGE_A(0, 0, 0); STAGE_A(0, 1, 0);
    STAGE_B(1, 0, 1); STAGE_B(1, 1, 1);
    VMW4;
    BAR;

    const int NITER = NTt >> 1;
    for (int it = 0; it < NITER; ++it) {
        const int t1 = 2 * it + 1;
        const int t2r = 2 * it + 2, t3r = 2 * it + 3;
        const int t2 = t2r < NTt ? t2r : 0;   // clamped dummies keep vmcnt uniform
        const int t3 = t3r < NTt ? t3r : 0;
        DSRA(0, 0); DSRB(0, 0, bF0); STAGE_A(1, 0, t1);
        BAR; MM(0, 0, bF0); BAR;
        DSRB(0, 1, bF1); STAGE_A(1, 1, t1);
        BAR; MM(0, 1, bF1); BAR;
        DSRA(0, 1); STAGE_B(0, 0, t2);
        BAR; MM(1, 1, bF1); BAR;
        STAGE_B(0, 1, t2); VMW4;
        BAR; MM(1, 0, bF0); BAR;
        DSRA(32768, 0); DSRB(32768, 0, bF0); STAGE_A(0, 0, t2);
        BAR; MM(0, 0, bF0); BAR;
        DSRB(32768, 1, bF1); STAGE_A(0, 1, t2);
        BAR; MM(0, 1, bF1); BAR;
        DSRA(32768, 1); STAGE_B(1, 0, t3);
        BAR; MM(1, 1, bF1); BAR;
        STAGE_B(1, 1, t3); VMW4;
        BAR; MM(1, 0, bF0); BAR;
    }
    asm volatile("s_waitcnt vmcnt(0)" ::: "memory");
    BAR;   // all waves drained their in-flight LDS writes before LDS reuse

    // ---- LDS-staged vectorized epilogue: 4 passes of 32 rows x 64 cols f32 ----
    const int orow = (l >> 4) << 2;
    float* eph = ((float*)lds) + w * 2176;   // wave-private 32x68 f32 (8.5 KB)
    const int ecol = (l & 15) << 2;
    const int erow4 = l >> 4;
#pragma unroll
    for (int pass = 0; pass < 4; pass++) {
#pragma unroll
        for (int mi = 0; mi < 2; mi++) {
            int mf = pass * 2 + mi;
#pragma unroll
            for (int nf = 0; nf < 4; nf++)
#pragma unroll
                for (int r = 0; r < 4; r++)
                    eph[(mi * 16 + orow + r) * 68 + nf * 16 + fcol] = acc[mf][nf][r];
        }
#pragma unroll
        for (int g = 0; g < 8; g++) {
            int lrow = g * 4 + erow4;
            f32x4 v = *(f32x4*)&eph[lrow * 68 + ecol];
            int row = m0 + wm * 128 + pass * 32 + lrow;
            int col = n0 + wn * 64 + ecol;
            if (BIAS) {
                float4 bb = *(const float4*)(bias + col);
                v[0] += bb.x; v[1] += bb.y; v[2] += bb.z; v[3] += bb.w;
            }
            if (RELU) {
#pragma unroll
                for (int q = 0; q < 4; q++) v[q] = v[q] > 0.f ? v[q] : 0.f;
            }
            size_t off = (size_t)row * N + col;
            if (SPLITK) off += (size_t)kz * (size_t)M * N;
            if (OUTBF) {
                u16x4 u;
                u[0] = f2bf(v[0]); u[1] = f2bf(v[1]); u[2] = f2bf(v[2]); u[3] = f2bf(v[3]);
                if (NTST) __builtin_nontemporal_store(u, (u16x4*)&((ushort*)Cout)[off]);
                else      *(u16x4*)&((ushort*)Cout)[off] = u;
            } else {
                if (NTST) __builtin_nontemporal_store(v, (f32x4*)&((float*)Cout)[off]);
                else      *(f32x4*)&((float*)Cout)[off] = v;
            }
        }
    }
}

// ---------------- 128x128 m97-style bf16 GEMM (GEMM2 + GEMM4) ----------------
template<bool SPLITK, bool BIAS, bool RELU, bool OUTBF>
__global__ __launch_bounds__(256) void k_gemm_bf(
    const ushort* __restrict__ A, const ushort* __restrict__ BT,
    const float* __restrict__ bias, void* __restrict__ Cout,
    int M, int N, int K, int kChunk) {
    __shared__ ushort lA[128 * 32];
    __shared__ ushort lB[128 * 32];
    const int t = threadIdx.x;
    const int w = t >> 6, l = t & 63;
    const int m0 = blockIdx.y * 128, n0 = blockIdx.x * 128;
    const int kLen = SPLITK ? kChunk : K;
    const int k0 = SPLITK ? blockIdx.z * kChunk : 0;
    const int srow = w * 16 + (l >> 2);
    const int skq = (l & 3) << 3;
    const ushort* gA = A + (size_t)(m0 + srow) * K + k0 + skq;
    const ushort* gB = BT + (size_t)(n0 + srow) * K + k0 + skq;
    ushort* lA0 = lA + w * 512;
    ushort* lB0 = lB + w * 512;
    const size_t str64 = (size_t)64 * K;
    const int wr = (w >> 1) << 6, wc = (w & 1) << 6;
    const int fcol = l & 15, fk = (l >> 4) << 3;

    f32x4 acc[4][4] = {};
    for (int kk = 0; kk < kLen; kk += 32) {
        __syncthreads();
        GLDS(gA + kk,         lA0);
        GLDS(gA + kk + str64, lA0 + 2048);
        GLDS(gB + kk,         lB0);
        GLDS(gB + kk + str64, lB0 + 2048);
        __syncthreads();
        short8v a[4], b[4];
#pragma unroll
        for (int f = 0; f < 4; f++) {
            a[f] = *(const short8v*)(lA + (wr + f * 16 + fcol) * 32 + fk);
            b[f] = *(const short8v*)(lB + (wc + f * 16 + fcol) * 32 + fk);
        }
#pragma unroll
        for (int i = 0; i < 4; i++)
#pragma unroll
            for (int j = 0; j < 4; j++)
                acc[i][j] = __builtin_amdgcn_mfma_f32_16x16x32_bf16(a[i], b[j], acc[i][j], 0, 0, 0);
    }
    const int orow = (l >> 4) << 2;
#pragma unroll
    for (int i = 0; i < 4; i++) {
#pragma unroll
        for (int j = 0; j < 4; j++) {
            int col = n0 + wc + j * 16 + fcol;
            float bv = BIAS ? bias[col] : 0.f;
#pragma unroll
            for (int r = 0; r < 4; r++) {
                int row = m0 + wr + i * 16 + orow + r;
                float v = acc[i][j][r] + bv;
                if (RELU) v = v > 0.f ? v : 0.f;
                if (OUTBF) {
                    ((ushort*)Cout)[(size_t)row * N + col] = f2bf(v);
                } else {
                    size_t off = (size_t)row * N + col;
                    if (SPLITK) off += (size_t)blockIdx.z * (size_t)M * N;
                    ((float*)Cout)[off] = v;
                }
            }
        }
    }
}

// ---------------- reduce GEMM1 bf16 partials + b1g + relu -> bf16 g1 (8 elems/thread) ----------------
__global__ __launch_bounds__(256) void k_red1(const ushort* __restrict__ part,
                                              const float* __restrict__ b1g,
                                              ushort* __restrict__ g1B) {
    int i8 = (blockIdx.x * 256 + threadIdx.x) * 8;   // over 512*2048
    float v[8];
#pragma unroll
    for (int k = 0; k < 8; k++) v[k] = b1g[(i8 + k) & (GPD - 1)];
#pragma unroll
    for (int q = 0; q < 16; q++) {
        uint4 pk = *(const uint4*)(part + (size_t)q * 1048576 + i8);
        const ushort* pu = (const ushort*)&pk;
#pragma unroll
        for (int k = 0; k < 8; k++) v[k] += bf2f(pu[k]);
    }
    ushort u[8];
#pragma unroll
    for (int k = 0; k < 8; k++) u[k] = f2bf(v[k] > 0.f ? v[k] : 0.f);
    *(uint4*)&g1B[i8] = *(uint4*)u;
}

// ---------------- build bf16 node matrix [NT][FEAT]; fused red2 (8 partials) ----------------
__global__ __launch_bounds__(256) void k_nodes(const float* __restrict__ part2,
                                               const float* __restrict__ b2g,
                                               const float* __restrict__ locf,
                                               ushort* __restrict__ nodesB) {
    int idx = blockIdx.x * 256 + threadIdx.x;   // over NT*144 = 2,506,752 16B-chunks
    int node = idx / 144, cc = idx - node * 144;
    int b = node / NPG, j = node - b * NPG;
    int c = cc * 8;
    ushort* dst = nodesB + (size_t)node * FEAT + c;
    if (j == 0) {
        float v[8];
        float4 b0 = *(const float4*)(b2g + c), b1 = *(const float4*)(b2g + c + 4);
        v[0] = b0.x; v[1] = b0.y; v[2] = b0.z; v[3] = b0.w;
        v[4] = b1.x; v[5] = b1.y; v[6] = b1.z; v[7] = b1.w;
#pragma unroll
        for (int q = 0; q < 8; q++) {
            const float* pp = part2 + (size_t)q * 589824 + (size_t)b * FEAT + c;
            float4 p0 = *(const float4*)pp, p1 = *(const float4*)(pp + 4);
            v[0] += p0.x; v[1] += p0.y; v[2] += p0.z; v[3] += p0.w;
            v[4] += p1.x; v[5] += p1.y; v[6] += p1.z; v[7] += p1.w;
        }
        ushort u[8];
#pragma unroll
        for (int k = 0; k < 8; k++) u[k] = f2bf(v[k]);
        *(uint4*)dst = *(uint4*)u;
    } else {
        const float* s = locf + ((size_t)b * 33 + (j - 1)) * FEAT + c;
        float4 v0 = *(const float4*)s, v1 = *(const float4*)(s + 4);
        ushort u[8] = {f2bf(v0.x), f2bf(v0.y), f2bf(v0.z), f2bf(v0.w),
                       f2bf(v1.x), f2bf(v1.y), f2bf(v1.z), f2bf(v1.w)};
        *(uint4*)dst = *(uint4*)u;
    }
}

// ---------------- fused GAT: scores + per-graph softmax + aggregation ----------------
// one block per graph, 512 threads. z staged RAW as bf16 (35 KB LDS -> 2 blocks/CU);
// bf2f on read reproduces the exact f32 values of the previous version -> bit-identical.
__global__ __launch_bounds__(512) void k_gat(const int* __restrict__ es, const int* __restrict__ ed,
                                             const ushort* __restrict__ zB,
                                             const float* __restrict__ a_src,
                                             const float* __restrict__ a_dst,
                                             ushort* __restrict__ gnnB) {
    __shared__ ushort ztB[NPG][520];                 // bf16 rows, 16B-aligned stride (35.4 KB)
    __shared__ float sps[NPG][NH], spd[NPG][NH], sm[NPG][NH], sden[NPG][NH];
    __shared__ float esc[EPG][NH];
    __shared__ int srcl[EPG], dll[EPG], order[EPG], cnt[NPG], bstart[NPG + 1];
    int b = blockIdx.x, t = threadIdx.x;
    for (int i = t; i < NPG * 64; i += 512) {        // raw 16B chunks
        int n = i >> 6, c0 = (i & 63) << 3;
        *(uint4*)&ztB[n][c0] = *(const uint4*)&zB[((size_t)b * NPG + n) * HA + c0];
    }
    for (int e = t; e < EPG; e += 512) {
        srcl[e] = es[b * EPG + e] - b * NPG;
        dll[e]  = ed[b * EPG + e] - b * NPG;
    }
    if (t < NPG) cnt[t] = 0;
    __syncthreads();
    {
        int wv = t >> 6, l = t & 63;
        for (int n = wv; n < NPG; n += 8) {
            float s[NH], d[NH];
#pragma unroll
            for (int i = 0; i < NH; i++) {
                float zv = bf2f(ztB[n][i * 64 + l]);
                s[i] = zv * a_src[i * 64 + l];
                d[i] = zv * a_dst[i * 64 + l];
            }
#pragma unroll
            for (int i = 0; i < NH; i++) {
#pragma unroll
                for (int off = 32; off > 0; off >>= 1) {
                    s[i] += __shfl_xor(s[i], off);
                    d[i] += __shfl_xor(d[i], off);
                }
            }
            if (l == 0) {
#pragma unroll
                for (int i = 0; i < NH; i++) { sps[n][i] = s[i]; spd[n][i] = d[i]; }
            }
        }
    }
    for (int e = t; e < EPG; e += 512) atomicAdd(&cnt[dll[e]], 1);
    __syncthreads();
    if (t == 0) {   // tiny serial prefix over 34 nodes
        int s = 0;
        for (int n = 0; n < NPG; n++) { bstart[n] = s; s += cnt[n]; }
        bstart[NPG] = s;
    }
    __syncthreads();
    // parallel rank: identical ascending-e bucket order to serial scatter
    if (t < EPG) {
        int myd = dll[t];
        int rank = 0;
        for (int e2 = 0; e2 < EPG; e2++) {
            int d2 = dll[e2];
            rank += (e2 < t && d2 == myd) ? 1 : 0;
        }
        order[bstart[myd] + rank] = t;
    }
    __syncthreads();
    for (int i = t; i < EPG * NH; i += 512) {
        int e = i >> 3, h = i & 7;
        float sc = sps[srcl[e]][h] + spd[dll[e]][h];
        esc[e][h] = sc > 0.f ? sc : 0.2f * sc;
    }
    __syncthreads();
    for (int i = t; i < NPG * NH; i += 512) {
        int n = i >> 3, h = i & 7;
        float m = -INFINITY;
        for (int j = bstart[n]; j < bstart[n + 1]; j++) m = fmaxf(m, esc[order[j]][h]);
        if (m == -INFINITY) m = 0.f;
        float den = 0.f;
        for (int j = bstart[n]; j < bstart[n + 1]; j++) den += expf(esc[order[j]][h] - m);
        sm[n][h] = m; sden[n][h] = den;
    }
    __syncthreads();
    for (int i = t; i < EPG * NH; i += 512) {
        int e = i >> 3, h = i & 7;
        esc[e][h] = expf(esc[e][h] - sm[dll[e]][h]) / (sden[dll[e]][h] + 1e-9f);
    }
    __syncthreads();
    for (int c = t; c < NPG * 64; c += 512) {
        int n = c >> 6, rem = c & 63, h = rem >> 3, d0 = (rem & 7) << 3;
        float acc[8] = {};
        for (int j = bstart[n]; j < bstart[n + 1]; j++) {
            int e = order[j];
            float a = esc[e][h];
            uint4 pk = *(const uint4*)&ztB[srcl[e]][h * 64 + d0];
            const ushort* pu = (const ushort*)&pk;
#pragma unroll
            for (int q = 0; q < 8; q++) acc[q] = fmaf(a, bf2f(pu[q]), acc[q]);
        }
        ushort u[8];
#pragma unroll
        for (int q = 0; q < 8; q++) u[q] = f2bf(acc[q]);
        *(uint4*)&gnnB[((size_t)b * NPG + n) * HA + h * 64 + d0] = *(uint4*)u;
    }
}

extern "C" void kernel_launch(void* const* d_in, const int* in_sizes, int n_in,
                              void* d_out, int out_size, void* d_ws, size_t ws_size,
                              hipStream_t stream) {
    const float* locf  = (const float*)d_in[0];
    const float* gf    = (const float*)d_in[1];
    const int*   ei    = (const int*)d_in[2];
    const float* W1g   = (const float*)d_in[3];
    const float* b1g   = (const float*)d_in[4];
    const float* W2g   = (const float*)d_in[5];
    const float* b2g   = (const float*)d_in[6];
    const float* Wp    = (const float*)d_in[7];
    const float* bp    = (const float*)d_in[8];
    const float* Wg    = (const float*)d_in[9];
    const float* a_src = (const float*)d_in[10];
    const float* a_dst = (const float*)d_in[11];
    const float* Wllm  = (const float*)d_in[12];
    const float* bllm  = (const float*)d_in[13];
    float* out = (float*)d_out;
    float* ws  = (float*)d_ws;
    const int* es = ei;
    const int* ed = ei + NE;

    // d_out scratch layout (float offsets; every region dead before GEMM5 overwrite)
    ushort* zB     = (ushort*)out;                      // bf16 z
    ushort* W1gT   = (ushort*)(out + 8912896);          // dead after GEMM1
    ushort* hB     = (ushort*)(out + 8912896);          // overlaps W1gT, written GEMM3
    ushort* poolB  = (ushort*)(out + 34078720);
    ushort* part1B = (ushort*)(out + 40370176);         // 16 x 512x2048 bf16 — dead after red1
    ushort* nodesB = (ushort*)(out + 40370176);         // overlaps dead part1B
    ushort* g1B    = (ushort*)(out + 57147392);
    ushort* W2gT   = (ushort*)(out + 57671680);
    ushort* WpT    = (ushort*)(out + 58851328);
    ushort* WgT    = (ushort*)(out + 59441152);
    float*  part2  = out + 59998208;                    // 8 x 512x1152 f32 (ends 64.7M < 71.3M)
    // d_ws layout (GEMM5 inputs live here, never in d_out)
    ushort* WllmT = (ushort*)ws;
    ushort* gnnB  = (ushort*)(ws + 1048576);

    // fused transposes (64x64, 16B writes) + pool
    k_prep<<<38368, 256, 0, stream>>>(W1g, W1gT, W2g, W2gT, Wp, WpT, Wg, WgT,
                                      Wllm, WllmT, gf, poolB);
    // GEMM1 (256sq 8-phase, split-K=16, z-map: per-XCD L2-resident A+B, single-fetch)
    k_gemm256<2, true, false, false, true, true><<<dim3(8, 2, 16), 512, 0, stream>>>(
        poolB, W1gT, nullptr, part1B, 512, GPD, C32, 1536);
    k_red1<<<512, 256, 0, stream>>>(part1B, b1g, g1B);
    // GEMM2 (128sq, split-K=8): [512,2048]x[2048,1152] -> f32 partials
    k_gemm_bf<true, false, false, false><<<dim3(9, 4, 8), 256, 0, stream>>>(
        g1B, W2gT, nullptr, part2, 512, FEAT, GPD, 256);
    // build node matrix (fused red2, 8 partials)
    k_nodes<<<9792, 256, 0, stream>>>(part2, b2g, locf, nodesB);
    // GEMM3 (256sq, swizzled): relu(nodes x Wp + bp) -> bf16 h [17408,1024]
    k_gemm256<1, false, true, true, true, false><<<dim3(4, 68), 512, 0, stream>>>(
        nodesB, WpT, bp, hB, NT, HID, FEAT, 0);
    // GEMM4 (128sq, full grid): z = h x Wg -> bf16 [17408,512]
    k_gemm_bf<false, false, false, true><<<dim3(4, 136), 256, 0, stream>>>(
        hB, WgT, nullptr, zB, NT, HA, HID, 0);
    // fused graph attention (512 threads, bf16 LDS z, 2 blocks/CU)
    k_gat<<<BB, 512, 0, stream>>>(es, ed, zB, a_src, a_dst, gnnB);
    // GEMM5 (256sq, swizzled, NT output stores): out = gnn x Wllm + bllm -> f32
    k_gemm256<1, false, true, false, false, true><<<dim3(16, 68), 512, 0, stream>>>(
        gnnB, WllmT, bllm, out, NT, LLM, HA, 0);
}